// Round 1
// baseline (122149.341 us; speedup 1.0000x reference)
//
#include <hip/hip_runtime.h>
#include <math.h>

// Seq2seq GRU encoder/decoder with exact JAX threefry sampling.
// R2 design: persistent kernels + device-scope grid barriers.
//   - 2048 graph nodes -> 4. The measured 42us/dispatch average showed the
//     "free" kernel-boundary barriers were the dominant cost.
//   - Math is BIT-IDENTICAL to the previous passing kernel (same fmaf
//     sequences, same unrolls, same RNG) so sampled tokens cannot flip.
//   - Grid barrier: single-word (gen<<16 | count), agent-scope acq/rel
//     (cross-XCD L2 coherence). Co-residency guaranteed by small footprint:
//     256 threads + ~6KB LDS => >=4 WGs/CU capacity, grids are 256/128 WGs.
//   - Barrier words overlaid on dead storage (enc: out probs row (b=0,t=1),
//     unwritten until decoder; dec: xT, dead after encoder) so the
//     workspace layout is unchanged.

#define BB 64
#define TT 512
#define VV 390
#define EE 256
#define HH 512

static __device__ __forceinline__ void tf2x32(unsigned k0, unsigned k1,
                                              unsigned x0, unsigned x1,
                                              unsigned &o0, unsigned &o1) {
  unsigned ks2 = k0 ^ k1 ^ 0x1BD11BDAu;
  x0 += k0; x1 += k1;
#define TFR(r) x0 += x1; x1 = (x1 << (r)) | (x1 >> (32 - (r))); x1 ^= x0;
  TFR(13) TFR(15) TFR(26) TFR(6)
  x0 += k1; x1 += ks2 + 1u;
  TFR(17) TFR(29) TFR(16) TFR(24)
  x0 += ks2; x1 += k0 + 2u;
  TFR(13) TFR(15) TFR(26) TFR(6)
  x0 += k0; x1 += k1 + 3u;
  TFR(17) TFR(29) TFR(16) TFR(24)
  x0 += k1; x1 += ks2 + 4u;
  TFR(13) TFR(15) TFR(26) TFR(6)
  x0 += ks2; x1 += k0 + 5u;
#undef TFR
  o0 = x0; o1 = x1;
}

static __device__ __forceinline__ float sigm(float x) {
  return 1.0f / (1.0f + expf(-x));
}

// 3 dot products of rows w0/w1/w2 (contiguous, len K) against X laid out
// [k][64] (batch-contiguous). Lane b = batch index -> coalesced X reads.
template <int K>
static __device__ __forceinline__ void dot3_kb(const float* __restrict__ X, int b,
    const float* __restrict__ w0, const float* __restrict__ w1,
    const float* __restrict__ w2, float &r0, float &r1, float &r2) {
  const float4* q0 = (const float4*)w0;
  const float4* q1 = (const float4*)w1;
  const float4* q2 = (const float4*)w2;
  float s0 = 0.f, s1 = 0.f, s2 = 0.f;
#pragma unroll 4
  for (int k4 = 0; k4 < (K >> 2); ++k4) {
    float4 u0 = q0[k4], u1 = q1[k4], u2 = q2[k4];
    int kb = (k4 << 8) + b;  // k4*4*64 + b
    float x0 = X[kb], x1 = X[kb + 64], x2 = X[kb + 128], x3 = X[kb + 192];
    s0 = fmaf(x0, u0.x, s0); s0 = fmaf(x1, u0.y, s0); s0 = fmaf(x2, u0.z, s0); s0 = fmaf(x3, u0.w, s0);
    s1 = fmaf(x0, u1.x, s1); s1 = fmaf(x1, u1.y, s1); s1 = fmaf(x2, u1.z, s1); s1 = fmaf(x3, u1.w, s1);
    s2 = fmaf(x0, u2.x, s2); s2 = fmaf(x1, u2.y, s2); s2 = fmaf(x2, u2.z, s2); s2 = fmaf(x3, u2.w, s2);
  }
  r0 = s0; r1 = s1; r2 = s2;
}

// Same but X is a contiguous per-lane row (embedding gather).
template <int K>
static __device__ __forceinline__ void dot3_row(const float* __restrict__ xrow,
    const float* __restrict__ w0, const float* __restrict__ w1,
    const float* __restrict__ w2, float &r0, float &r1, float &r2) {
  const float4* xq = (const float4*)xrow;
  const float4* q0 = (const float4*)w0;
  const float4* q1 = (const float4*)w1;
  const float4* q2 = (const float4*)w2;
  float s0 = 0.f, s1 = 0.f, s2 = 0.f;
#pragma unroll 4
  for (int k4 = 0; k4 < (K >> 2); ++k4) {
    float4 x = xq[k4];
    float4 u0 = q0[k4], u1 = q1[k4], u2 = q2[k4];
    s0 = fmaf(x.x, u0.x, s0); s0 = fmaf(x.y, u0.y, s0); s0 = fmaf(x.z, u0.z, s0); s0 = fmaf(x.w, u0.w, s0);
    s1 = fmaf(x.x, u1.x, s1); s1 = fmaf(x.y, u1.y, s1); s1 = fmaf(x.z, u1.z, s1); s1 = fmaf(x.w, u1.w, s1);
    s2 = fmaf(x.x, u2.x, s2); s2 = fmaf(x.y, u2.y, s2); s2 = fmaf(x.z, u2.z, s2); s2 = fmaf(x.w, u2.w, s2);
  }
  r0 = s0; r1 = s1; r2 = s2;
}

// Single-word grid barrier: word = (generation << 16) | arrived_count.
// nwg <= 256 so count never overflows into gen; <= 2046 barriers/run so gen
// never wraps 16 bits. Agent scope: release flushes XCD L2 (buffer_wbl2),
// acquire invalidates (buffer_inv) -> cross-XCD coherence for h/tok/rng.
static __device__ __forceinline__ void gridbar(unsigned* bar, unsigned nwg) {
  __syncthreads();  // compiler emits s_waitcnt vmcnt(0) before s_barrier:
                    // all this WG's stores are in L2 before the release.
  if (threadIdx.x == 0) {
    unsigned v = __hip_atomic_fetch_add(bar, 1u, __ATOMIC_ACQ_REL,
                                        __HIP_MEMORY_SCOPE_AGENT);
    unsigned gen = v >> 16;
    if ((v & 0xffffu) == nwg - 1u) {
      // Last arriver: reset count, bump generation. No other WG can touch
      // the word until this store lands (spinners only read).
      __hip_atomic_store(bar, (gen + 1u) << 16, __ATOMIC_RELEASE,
                         __HIP_MEMORY_SCOPE_AGENT);
    } else {
      while ((__hip_atomic_load(bar, __ATOMIC_RELAXED,
                                __HIP_MEMORY_SCOPE_AGENT) >> 16) == gen)
        __builtin_amdgcn_s_sleep(1);
      __builtin_amdgcn_fence(__ATOMIC_ACQUIRE, "agent");
    }
  }
  __syncthreads();
}

__global__ __launch_bounds__(256) void k_init(float* out,
    float* h1buf, float* h2buf, int* tok, unsigned* rng, unsigned* ebar) {
  int wg = blockIdx.x, tid = threadIdx.x;
  for (int i = wg * 256 + tid; i < HH * BB; i += 64 * 256) {
    h1buf[i] = 0.f;  // slot 0 only (slot 1 always written before read)
    h2buf[i] = 0.f;
  }
  // outputs[:,0,:] = one_hot(388); max_output[:,0] = 388
  for (int v = tid; v < VV; v += 256)
    out[(size_t)wg * TT * VV + v] = (v == 388) ? 1.0f : 0.0f;
  if (tid == 0) {
    out[(size_t)BB * TT * VV + (size_t)wg * TT] = 388.0f;
    tok[wg] = 388;
    if (wg == 0) {
      rng[0] = 0u; rng[1] = 42u; rng[2] = 0u; rng[3] = 0u;
      ebar[0] = 0u;  // encoder barrier word (lives in out[(0,1,:)], dead
                     // until decoder writes that probs row)
    }
  }
}

// x[t][e][b] = sum_v input[b][t][v] * emb[v][e]; one WG per t.
__global__ __launch_bounds__(256) void k_xgemm(const float* __restrict__ input,
    const float* __restrict__ emb, float* __restrict__ xT) {
  int t = blockIdx.x, tid = threadIdx.x;
  int s = tid >> 6, b = tid & 63;
  __shared__ float lin[64 * 65];  // [kk][b], stride 65 -> conflict-free both ways
  float4 acc[16];
#pragma unroll
  for (int i = 0; i < 16; ++i) acc[i] = make_float4(0.f, 0.f, 0.f, 0.f);
  for (int k0 = 0; k0 < VV; k0 += 64) {
    int kmax = min(64, VV - k0);
    __syncthreads();
#pragma unroll
    for (int r = 0; r < 16; ++r) {
      int idx = r * 256 + tid;
      int b2 = idx >> 6, kk = idx & 63;
      if (kk < kmax)
        lin[kk * 65 + b2] = input[((size_t)b2 * TT + t) * VV + k0 + kk];
    }
    __syncthreads();
    for (int kk = 0; kk < kmax; ++kk) {
      float xv = lin[kk * 65 + b];
      const float4* er = (const float4*)(emb + (size_t)(k0 + kk) * EE);
#pragma unroll
      for (int i = 0; i < 16; ++i) {
        float4 w = er[s + 4 * i];  // wave-uniform
        acc[i].x = fmaf(xv, w.x, acc[i].x);
        acc[i].y = fmaf(xv, w.y, acc[i].y);
        acc[i].z = fmaf(xv, w.z, acc[i].z);
        acc[i].w = fmaf(xv, w.w, acc[i].w);
      }
    }
  }
  float* dst0 = xT + (size_t)t * (EE * 64);
#pragma unroll
  for (int i = 0; i < 16; ++i) {
    int e = (s + 4 * i) * 4;
    float* d = dst0 + e * 64 + b;
    d[0] = acc[i].x; d[64] = acc[i].y; d[128] = acc[i].z; d[192] = acc[i].w;
  }
}

// Persistent encoder: the old 513 launches collapsed into one kernel.
// Per iteration: WGs 0..127 do layer0 step t, WGs 128..255 do layer1 step
// t-1 (pipelined exactly as before); one grid barrier replaces the launch.
__global__ __launch_bounds__(256) void k_enc_persist(
    const float* __restrict__ xT, float* h1buf, float* h2buf,
    const float* __restrict__ Wih0, const float* __restrict__ Whh0,
    const float* __restrict__ bih0, const float* __restrict__ bhh0,
    const float* __restrict__ Wih1, const float* __restrict__ Whh1,
    const float* __restrict__ bih1, const float* __restrict__ bhh1,
    unsigned* ebar, unsigned* dbar) {
  int wg = blockIdx.x, tid = threadIdx.x;
  int s = tid >> 6, b = tid & 63;
  for (int t = 0; t <= TT; ++t) {
    const float* h1_r = h1buf + (t & 1) * (HH * BB);        // h1[t-1]
    float* h1_w = h1buf + ((t + 1) & 1) * (HH * BB);        // h1[t]
    if (wg < 128) {
      if (t < TT) {
        int j = wg * 4 + s;
        float ar, az, an, hr, hz, hn;
        dot3_kb<EE>(xT + (size_t)t * (EE * 64), b,
                    Wih0 + (size_t)j * EE, Wih0 + (size_t)(512 + j) * EE,
                    Wih0 + (size_t)(1024 + j) * EE, ar, az, an);
        dot3_kb<HH>(h1_r, b,
                    Whh0 + (size_t)j * HH, Whh0 + (size_t)(512 + j) * HH,
                    Whh0 + (size_t)(1024 + j) * HH, hr, hz, hn);
        float r = sigm((ar + bih0[j]) + (hr + bhh0[j]));
        float z = sigm((az + bih0[512 + j]) + (hz + bhh0[512 + j]));
        float n = tanhf((an + bih0[1024 + j]) + r * (hn + bhh0[1024 + j]));
        h1_w[j * 64 + b] = (1.0f - z) * n + z * h1_r[j * 64 + b];
      }
    } else {
      if (t >= 1) {  // layer1 processes step t-1
        int j = (wg - 128) * 4 + s;
        const float* h2_r = h2buf + ((t + 1) & 1) * (HH * BB);  // h2[t-2]
        float* h2_w = h2buf + (t & 1) * (HH * BB);              // h2[t-1]
        float ar, az, an, hr, hz, hn;
        dot3_kb<HH>(h1_r, b,   // input = seq1[t-1] = h1[t-1]
                    Wih1 + (size_t)j * HH, Wih1 + (size_t)(512 + j) * HH,
                    Wih1 + (size_t)(1024 + j) * HH, ar, az, an);
        dot3_kb<HH>(h2_r, b,
                    Whh1 + (size_t)j * HH, Whh1 + (size_t)(512 + j) * HH,
                    Whh1 + (size_t)(1024 + j) * HH, hr, hz, hn);
        float r = sigm((ar + bih1[j]) + (hr + bhh1[j]));
        float z = sigm((az + bih1[512 + j]) + (hz + bhh1[512 + j]));
        float n = tanhf((an + bih1[1024 + j]) + r * (hn + bhh1[1024 + j]));
        h2_w[j * 64 + b] = (1.0f - z) * n + z * h2_r[j * 64 + b];
      }
    }
    // Initialize the decoder's barrier word (lives at xT[0], which is dead
    // by now: layer0's last xT read was t=511). Kernel-end flush + the final
    // gridbar's release make it visible to k_dec_persist.
    if (t == TT && wg == 0 && tid == 0) dbar[0] = 0u;
    gridbar(ebar, 256u);
  }
}

// Persistent decoder: the old 511*3 launches collapsed into one kernel.
// Grid = 128 WGs (phases A/B use all 128, phase C uses 64).
__global__ __launch_bounds__(256) void k_dec_persist(
    float* h1buf, float* h2buf,
    const float* __restrict__ demb,
    const float* __restrict__ dWih0, const float* __restrict__ dWhh0,
    const float* __restrict__ dbih0, const float* __restrict__ dbhh0,
    const float* __restrict__ dWih1, const float* __restrict__ dWhh1,
    const float* __restrict__ dbih1, const float* __restrict__ dbhh1,
    const float* __restrict__ Wp1, const float* __restrict__ bp1,
    const float* __restrict__ Wp2, const float* __restrict__ bp2,
    float* out, int* tok, unsigned* rng, unsigned* dbar) {
  int wg = blockIdx.x, tid = threadIdx.x;
  int s = tid >> 6, b = tid & 63;
  __shared__ __align__(16) float lh[HH];
  __shared__ __align__(16) float lhid[HH];
  __shared__ float lv[VV];
  __shared__ float rf[8];
  __shared__ int ri[4];
  for (int d = 0; d < TT - 1; ++d) {
    // ---------------- phase A: decoder layer0 (all 128 WGs) ----------------
    {
      const float* h1_r = h1buf + (d & 1) * (HH * BB);
      float* h1_w = h1buf + ((d + 1) & 1) * (HH * BB);
      int j = wg * 4 + s;
      int tk = tok[b];
      float ar, az, an, hr, hz, hn;
      dot3_row<EE>(demb + (size_t)tk * EE,
                   dWih0 + (size_t)j * EE, dWih0 + (size_t)(512 + j) * EE,
                   dWih0 + (size_t)(1024 + j) * EE, ar, az, an);
      dot3_kb<HH>(h1_r, b,
                  dWhh0 + (size_t)j * HH, dWhh0 + (size_t)(512 + j) * HH,
                  dWhh0 + (size_t)(1024 + j) * HH, hr, hz, hn);
      float r = sigm((ar + dbih0[j]) + (hr + dbhh0[j]));
      float z = sigm((az + dbih0[512 + j]) + (hz + dbhh0[512 + j]));
      float n = tanhf((an + dbih0[1024 + j]) + r * (hn + dbhh0[1024 + j]));
      h1_w[j * 64 + b] = (1.0f - z) * n + z * h1_r[j * 64 + b];
    }
    gridbar(dbar, 128u);
    // ---------------- phase B: decoder layer1 (all 128 WGs) ----------------
    {
      const float* h1n = h1buf + ((d + 1) & 1) * (HH * BB);
      const float* h2r = h2buf + (d & 1) * (HH * BB);
      float* h2w = h2buf + ((d + 1) & 1) * (HH * BB);
      int j = wg * 4 + s;
      float ar, az, an, hr, hz, hn;
      dot3_kb<HH>(h1n, b,
                  dWih1 + (size_t)j * HH, dWih1 + (size_t)(512 + j) * HH,
                  dWih1 + (size_t)(1024 + j) * HH, ar, az, an);
      dot3_kb<HH>(h2r, b,
                  dWhh1 + (size_t)j * HH, dWhh1 + (size_t)(512 + j) * HH,
                  dWhh1 + (size_t)(1024 + j) * HH, hr, hz, hn);
      float r = sigm((ar + dbih1[j]) + (hr + dbhh1[j]));
      float z = sigm((az + dbih1[512 + j]) + (hz + dbhh1[512 + j]));
      float n = tanhf((an + dbih1[1024 + j]) + r * (hn + dbhh1[1024 + j]));
      h2w[j * 64 + b] = (1.0f - z) * n + z * h2r[j * 64 + b];
    }
    gridbar(dbar, 128u);
    // ------------- phase C: head + softmax + sampling (WGs 0..63) ----------
    if (wg < 64) {
      int brow = wg;
      const float* h2 = h2buf + ((d + 1) & 1) * (HH * BB);
      lh[tid] = h2[tid * 64 + brow];
      lh[tid + 256] = h2[(tid + 256) * 64 + brow];
      __syncthreads();
      // hid = LeakyReLU(h2 @ Wp1^T + bp1)
      for (int c = tid; c < HH; c += 256) {
        const float4* w = (const float4*)(Wp1 + (size_t)c * HH);
        float a = 0.f;
#pragma unroll 4
        for (int k4 = 0; k4 < HH / 4; ++k4) {
          float4 q = w[k4];
          float4 hv = *(const float4*)&lh[k4 * 4];
          a = fmaf(hv.x, q.x, a); a = fmaf(hv.y, q.y, a);
          a = fmaf(hv.z, q.z, a); a = fmaf(hv.w, q.w, a);
        }
        a += bp1[c];
        lhid[c] = (a >= 0.f) ? a : 0.1f * a;
      }
      __syncthreads();
      // logits = hid @ Wp2^T + bp2
      for (int c = tid; c < VV; c += 256) {
        const float4* w = (const float4*)(Wp2 + (size_t)c * HH);
        float a = 0.f;
#pragma unroll 4
        for (int k4 = 0; k4 < HH / 4; ++k4) {
          float4 q = w[k4];
          float4 hv = *(const float4*)&lhid[k4 * 4];
          a = fmaf(hv.x, q.x, a); a = fmaf(hv.y, q.y, a);
          a = fmaf(hv.z, q.z, a); a = fmaf(hv.w, q.w, a);
        }
        lv[c] = a + bp2[c];
      }
      __syncthreads();
      // row max
      float m = -INFINITY;
      for (int c = tid; c < VV; c += 256) m = fmaxf(m, lv[c]);
      for (int off = 32; off > 0; off >>= 1) m = fmaxf(m, __shfl_down(m, off, 64));
      if ((tid & 63) == 0) rf[tid >> 6] = m;
      __syncthreads();
      if (tid == 0) rf[4] = fmaxf(fmaxf(rf[0], rf[1]), fmaxf(rf[2], rf[3]));
      __syncthreads();
      m = rf[4];
      // sk = TF(rng_d, (0,1)); gumbel-argmax (first-index ties, like jnp.argmax)
      unsigned k0r = rng[(d & 1) * 2], k1r = rng[(d & 1) * 2 + 1];
      unsigned sk0, sk1;
      tf2x32(k0r, k1r, 0u, 1u, sk0, sk1);
      float by = -INFINITY; int bc = 0x7fffffff;
      for (int c = tid; c < VV; c += 256) {
        unsigned o0, o1;
        tf2x32(sk0, sk1, 0u, (unsigned)(brow * VV + c), o0, o1);
        unsigned bits = o0 ^ o1;  // partitionable-mode fold
        float f = __uint_as_float(0x3f800000u | (bits >> 9)) - 1.0f;
        float u = (f > 0.f) ? f : 1.17549435e-38f;
        float g = (float)(-log(-log((double)u)));
        float y = lv[c] + g;
        if (y > by || (y == by && c < bc)) { by = y; bc = c; }
      }
      for (int off = 32; off > 0; off >>= 1) {
        float oy = __shfl_down(by, off, 64);
        int oc = __shfl_down(bc, off, 64);
        if (oy > by || (oy == by && oc < bc)) { by = oy; bc = oc; }
      }
      if ((tid & 63) == 0) { rf[tid >> 6] = by; ri[tid >> 6] = bc; }
      __syncthreads();
      if (tid == 0) {
        by = rf[0]; bc = ri[0];
        for (int w2 = 1; w2 < 4; ++w2)
          if (rf[w2] > by || (rf[w2] == by && ri[w2] < bc)) { by = rf[w2]; bc = ri[w2]; }
        tok[brow] = bc;
        out[(size_t)BB * TT * VV + (size_t)brow * TT + (d + 1)] = (float)bc;
        if (brow == 0) {  // rng_{d+1} = TF(rng_d, (0,0))
          unsigned n0, n1;
          tf2x32(k0r, k1r, 0u, 0u, n0, n1);
          rng[((d + 1) & 1) * 2] = n0;
          rng[((d + 1) & 1) * 2 + 1] = n1;
        }
      }
      __syncthreads();
      // softmax probs
      float e0 = 0.f, e1 = 0.f, ssum = 0.f;
      {
        int c = tid;
        if (c < VV) { e0 = expf(lv[c] - m); ssum += e0; }
        c = tid + 256;
        if (c < VV) { e1 = expf(lv[c] - m); ssum += e1; }
      }
      for (int off = 32; off > 0; off >>= 1) ssum += __shfl_down(ssum, off, 64);
      if ((tid & 63) == 0) rf[tid >> 6] = ssum;
      __syncthreads();
      if (tid == 0) rf[4] = (rf[0] + rf[1]) + (rf[2] + rf[3]);
      __syncthreads();
      float S = rf[4];
      float* orow = out + ((size_t)brow * TT + (d + 1)) * VV;
      if (tid < VV) orow[tid] = e0 / S;
      if (tid + 256 < VV) orow[tid + 256] = e1 / S;
    }
    gridbar(dbar, 128u);
  }
}

extern "C" void kernel_launch(void* const* d_in, const int* in_sizes, int n_in,
                              void* d_out, int out_size, void* d_ws, size_t ws_size,
                              hipStream_t stream) {
  (void)in_sizes; (void)n_in; (void)out_size; (void)ws_size;
  const float* input = (const float*)d_in[0];
  const float* e_emb = (const float*)d_in[1];
  const float* eWih0 = (const float*)d_in[2];
  const float* eWhh0 = (const float*)d_in[3];
  const float* ebih0 = (const float*)d_in[4];
  const float* ebhh0 = (const float*)d_in[5];
  const float* eWih1 = (const float*)d_in[6];
  const float* eWhh1 = (const float*)d_in[7];
  const float* ebih1 = (const float*)d_in[8];
  const float* ebhh1 = (const float*)d_in[9];
  const float* d_emb = (const float*)d_in[10];
  const float* dWih0 = (const float*)d_in[11];
  const float* dWhh0 = (const float*)d_in[12];
  const float* dbih0 = (const float*)d_in[13];
  const float* dbhh0 = (const float*)d_in[14];
  const float* dWih1 = (const float*)d_in[15];
  const float* dWhh1 = (const float*)d_in[16];
  const float* dbih1 = (const float*)d_in[17];
  const float* dbhh1 = (const float*)d_in[18];
  const float* Wp1   = (const float*)d_in[19];
  const float* bp1   = (const float*)d_in[20];
  const float* Wp2   = (const float*)d_in[21];
  const float* bp2   = (const float*)d_in[22];
  float* out = (float*)d_out;

  // ws layout (~34.1 MB, unchanged): xT [512][256][64] | h1 pp | h2 pp | tok | rng
  float* xT = (float*)d_ws;
  float* h1buf = xT + (size_t)TT * EE * 64;
  float* h2buf = h1buf + 2 * HH * BB;
  int* tok = (int*)(h2buf + 2 * HH * BB);
  unsigned* rng = (unsigned*)(tok + 64);
  // Barrier words overlaid on dead storage (no ws growth):
  //  - ebar: out probs row (b=0,t=1) -- unwritten until decoder d=0 phase C,
  //    which runs after the encoder kernel has fully completed.
  //  - dbar: xT[0] -- dead after encoder (initialized inside k_enc_persist
  //    at t==TT, i.e. after the last xT read at t==511).
  unsigned* ebar = (unsigned*)(out + VV);
  unsigned* dbar = (unsigned*)xT;

  k_init<<<64, 256, 0, stream>>>(out, h1buf, h2buf, tok, rng, ebar);
  k_xgemm<<<TT, 256, 0, stream>>>(input, e_emb, xT);
  k_enc_persist<<<256, 256, 0, stream>>>(xT, h1buf, h2buf,
      eWih0, eWhh0, ebih0, ebhh0, eWih1, eWhh1, ebih1, ebhh1, ebar, dbar);
  k_dec_persist<<<128, 256, 0, stream>>>(h1buf, h2buf, d_emb,
      dWih0, dWhh0, dbih0, dbhh0, dWih1, dWhh1, dbih1, dbhh1,
      Wp1, bp1, Wp2, bp2, out, tok, rng, dbar);
}

// Round 2
// 84243.823 us; speedup vs baseline: 1.4500x; 1.4500x over previous
//
#include <hip/hip_runtime.h>
#include <math.h>

// Seq2seq GRU encoder/decoder with exact JAX threefry sampling.
// R3 design: persistent kernels + FENCELESS sc1 barriers.
//   R1 post-mortem: gridbar's ACQ_REL agent fence per WG arrival emits
//   buffer_wbl2/buffer_inv (full L2 writeback/invalidate) -> ~0.6us/arrival
//   -> 165us/barrier. Fix: ALL cross-WG data uses relaxed agent-scope
//   atomics (compile to global_load/store sc1=1: bypass the non-coherent
//   per-XCD L2, coherent at memory-side L3). Barrier = flag-store +
//   master-poll + go-broadcast: zero RMW, zero fences. Ordering between a
//   WG's h-stores and its flag-store comes from __syncthreads()'s
//   s_waitcnt vmcnt(0).
//   Math is BIT-IDENTICAL to the R1-passing kernel (same fmaf chains, same
//   RNG) -> absmax must stay exactly 1.525879e-05; any deviation means the
//   coherence protocol leaked a stale value.
//   Decoder head restructured feature-parallel (C1 hid / C2 logits / C3
//   sample): head weights read once per step grid-wide (1.8MB) instead of
//   per batch-row (115MB/step).

#define BB 64
#define TT 512
#define VV 390
#define EE 256
#define HH 512

static __device__ __forceinline__ void tf2x32(unsigned k0, unsigned k1,
                                              unsigned x0, unsigned x1,
                                              unsigned &o0, unsigned &o1) {
  unsigned ks2 = k0 ^ k1 ^ 0x1BD11BDAu;
  x0 += k0; x1 += k1;
#define TFR(r) x0 += x1; x1 = (x1 << (r)) | (x1 >> (32 - (r))); x1 ^= x0;
  TFR(13) TFR(15) TFR(26) TFR(6)
  x0 += k1; x1 += ks2 + 1u;
  TFR(17) TFR(29) TFR(16) TFR(24)
  x0 += ks2; x1 += k0 + 2u;
  TFR(13) TFR(15) TFR(26) TFR(6)
  x0 += k0; x1 += k1 + 3u;
  TFR(17) TFR(29) TFR(16) TFR(24)
  x0 += k1; x1 += ks2 + 4u;
  TFR(13) TFR(15) TFR(26) TFR(6)
  x0 += ks2; x1 += k0 + 5u;
#undef TFR
  o0 = x0; o1 = x1;
}

static __device__ __forceinline__ float sigm(float x) {
  return 1.0f / (1.0f + expf(-x));
}

// ---- agent-scope relaxed (sc1) memory helpers: bypass non-coherent L2 ----
static __device__ __forceinline__ unsigned ldu_a(const unsigned* p) {
  return __hip_atomic_load((unsigned*)p, __ATOMIC_RELAXED,
                           __HIP_MEMORY_SCOPE_AGENT);
}
static __device__ __forceinline__ void stu_a(unsigned* p, unsigned v) {
  __hip_atomic_store(p, v, __ATOMIC_RELAXED, __HIP_MEMORY_SCOPE_AGENT);
}
static __device__ __forceinline__ float ldf_a(const float* p) {
  return __uint_as_float(ldu_a((const unsigned*)p));
}
static __device__ __forceinline__ void stf_a(float* p, float v) {
  stu_a((unsigned*)p, __float_as_uint(v));
}

// 3 dot products of rows w0/w1/w2 (contiguous, len K) against X laid out
// [k][64] (batch-contiguous). Plain-load variant (read-only cached X).
template <int K>
static __device__ __forceinline__ void dot3_kb(const float* __restrict__ X, int b,
    const float* __restrict__ w0, const float* __restrict__ w1,
    const float* __restrict__ w2, float &r0, float &r1, float &r2) {
  const float4* q0 = (const float4*)w0;
  const float4* q1 = (const float4*)w1;
  const float4* q2 = (const float4*)w2;
  float s0 = 0.f, s1 = 0.f, s2 = 0.f;
#pragma unroll 4
  for (int k4 = 0; k4 < (K >> 2); ++k4) {
    float4 u0 = q0[k4], u1 = q1[k4], u2 = q2[k4];
    int kb = (k4 << 8) + b;  // k4*4*64 + b
    float x0 = X[kb], x1 = X[kb + 64], x2 = X[kb + 128], x3 = X[kb + 192];
    s0 = fmaf(x0, u0.x, s0); s0 = fmaf(x1, u0.y, s0); s0 = fmaf(x2, u0.z, s0); s0 = fmaf(x3, u0.w, s0);
    s1 = fmaf(x0, u1.x, s1); s1 = fmaf(x1, u1.y, s1); s1 = fmaf(x2, u1.z, s1); s1 = fmaf(x3, u1.w, s1);
    s2 = fmaf(x0, u2.x, s2); s2 = fmaf(x1, u2.y, s2); s2 = fmaf(x2, u2.z, s2); s2 = fmaf(x3, u2.w, s2);
  }
  r0 = s0; r1 = s1; r2 = s2;
}

// sc1 variant: X is cross-WG mutable state (h1/h2/hid) -> coherent loads.
template <int K>
static __device__ __forceinline__ void dot3_kb_a(const float* __restrict__ X, int b,
    const float* __restrict__ w0, const float* __restrict__ w1,
    const float* __restrict__ w2, float &r0, float &r1, float &r2) {
  const float4* q0 = (const float4*)w0;
  const float4* q1 = (const float4*)w1;
  const float4* q2 = (const float4*)w2;
  float s0 = 0.f, s1 = 0.f, s2 = 0.f;
#pragma unroll 4
  for (int k4 = 0; k4 < (K >> 2); ++k4) {
    float4 u0 = q0[k4], u1 = q1[k4], u2 = q2[k4];
    int kb = (k4 << 8) + b;
    float x0 = ldf_a(X + kb), x1 = ldf_a(X + kb + 64);
    float x2 = ldf_a(X + kb + 128), x3 = ldf_a(X + kb + 192);
    s0 = fmaf(x0, u0.x, s0); s0 = fmaf(x1, u0.y, s0); s0 = fmaf(x2, u0.z, s0); s0 = fmaf(x3, u0.w, s0);
    s1 = fmaf(x0, u1.x, s1); s1 = fmaf(x1, u1.y, s1); s1 = fmaf(x2, u1.z, s1); s1 = fmaf(x3, u1.w, s1);
    s2 = fmaf(x0, u2.x, s2); s2 = fmaf(x1, u2.y, s2); s2 = fmaf(x2, u2.z, s2); s2 = fmaf(x3, u2.w, s2);
  }
  r0 = s0; r1 = s1; r2 = s2;
}

// Single row dot (sc1 X), same fp order as the old per-c head loops.
template <int K>
static __device__ __forceinline__ float dot1_kb_a(const float* __restrict__ X, int b,
    const float* __restrict__ w) {
  const float4* q = (const float4*)w;
  float s = 0.f;
#pragma unroll 4
  for (int k4 = 0; k4 < (K >> 2); ++k4) {
    float4 u = q[k4];
    int kb = (k4 << 8) + b;
    s = fmaf(ldf_a(X + kb), u.x, s);
    s = fmaf(ldf_a(X + kb + 64), u.y, s);
    s = fmaf(ldf_a(X + kb + 128), u.z, s);
    s = fmaf(ldf_a(X + kb + 192), u.w, s);
  }
  return s;
}

// X is a contiguous per-lane row (embedding gather, read-only).
template <int K>
static __device__ __forceinline__ void dot3_row(const float* __restrict__ xrow,
    const float* __restrict__ w0, const float* __restrict__ w1,
    const float* __restrict__ w2, float &r0, float &r1, float &r2) {
  const float4* xq = (const float4*)xrow;
  const float4* q0 = (const float4*)w0;
  const float4* q1 = (const float4*)w1;
  const float4* q2 = (const float4*)w2;
  float s0 = 0.f, s1 = 0.f, s2 = 0.f;
#pragma unroll 4
  for (int k4 = 0; k4 < (K >> 2); ++k4) {
    float4 x = xq[k4];
    float4 u0 = q0[k4], u1 = q1[k4], u2 = q2[k4];
    s0 = fmaf(x.x, u0.x, s0); s0 = fmaf(x.y, u0.y, s0); s0 = fmaf(x.z, u0.z, s0); s0 = fmaf(x.w, u0.w, s0);
    s1 = fmaf(x.x, u1.x, s1); s1 = fmaf(x.y, u1.y, s1); s1 = fmaf(x.z, u1.z, s1); s1 = fmaf(x.w, u1.w, s1);
    s2 = fmaf(x.x, u2.x, s2); s2 = fmaf(x.y, u2.y, s2); s2 = fmaf(x.z, u2.z, s2); s2 = fmaf(x.w, u2.w, s2);
  }
  r0 = s0; r1 = s1; r2 = s2;
}

// Fenceless grid barrier. flags[NWG], go[NWG]: monotonic epochs.
// Entry __syncthreads() emits s_waitcnt vmcnt(0): all of this WG's sc1
// stores are at the coherent point before the flag publishes them.
template <int NWG>
static __device__ __forceinline__ void flagbar(unsigned* flags, unsigned* go,
                                               int wg, unsigned epoch) {
  __syncthreads();
  int tid = threadIdx.x;
  if (wg == 0) {
    if (tid == 0) stu_a(flags + 0, epoch);
    while (!__syncthreads_and((int)(ldu_a(flags + (tid & (NWG - 1))) >= epoch))) {}
    if (tid < NWG) stu_a(go + tid, epoch);
    // all flags observed; WG0 proceeds (its go-stores are fire-and-forget)
  } else {
    if (tid == 0) {
      stu_a(flags + wg, epoch);
      while (ldu_a(go + wg) < epoch) __builtin_amdgcn_s_sleep(1);
    }
    __syncthreads();
  }
}

__global__ __launch_bounds__(256) void k_init(float* out,
    float* h1buf, float* h2buf, int* tok, unsigned* ebase) {
  int wg = blockIdx.x, tid = threadIdx.x;
  for (int i = wg * 256 + tid; i < HH * BB; i += 64 * 256) {
    h1buf[i] = 0.f;  // slot 0 only (slot 1 always written before read)
    h2buf[i] = 0.f;
  }
  // outputs[:,0,:] = one_hot(388); max_output[:,0] = 388
  for (int v = tid; v < VV; v += 256)
    out[(size_t)wg * TT * VV + v] = (v == 388) ? 1.0f : 0.0f;
  if (wg == 0) {  // encoder barrier words: eflags[256] | ego[256]
    ebase[tid] = 0u;
    ebase[tid + 256] = 0u;
  }
  if (tid == 0) {
    out[(size_t)BB * TT * VV + (size_t)wg * TT] = 388.0f;
    tok[wg] = 388;
  }
}

// x[t][e][b] = sum_v input[b][t][v] * emb[v][e]; one WG per t.
__global__ __launch_bounds__(256) void k_xgemm(const float* __restrict__ input,
    const float* __restrict__ emb, float* __restrict__ xT) {
  int t = blockIdx.x, tid = threadIdx.x;
  int s = tid >> 6, b = tid & 63;
  __shared__ float lin[64 * 65];
  float4 acc[16];
#pragma unroll
  for (int i = 0; i < 16; ++i) acc[i] = make_float4(0.f, 0.f, 0.f, 0.f);
  for (int k0 = 0; k0 < VV; k0 += 64) {
    int kmax = min(64, VV - k0);
    __syncthreads();
#pragma unroll
    for (int r = 0; r < 16; ++r) {
      int idx = r * 256 + tid;
      int b2 = idx >> 6, kk = idx & 63;
      if (kk < kmax)
        lin[kk * 65 + b2] = input[((size_t)b2 * TT + t) * VV + k0 + kk];
    }
    __syncthreads();
    for (int kk = 0; kk < kmax; ++kk) {
      float xv = lin[kk * 65 + b];
      const float4* er = (const float4*)(emb + (size_t)(k0 + kk) * EE);
#pragma unroll
      for (int i = 0; i < 16; ++i) {
        float4 w = er[s + 4 * i];
        acc[i].x = fmaf(xv, w.x, acc[i].x);
        acc[i].y = fmaf(xv, w.y, acc[i].y);
        acc[i].z = fmaf(xv, w.z, acc[i].z);
        acc[i].w = fmaf(xv, w.w, acc[i].w);
      }
    }
  }
  float* dst0 = xT + (size_t)t * (EE * 64);
#pragma unroll
  for (int i = 0; i < 16; ++i) {
    int e = (s + 4 * i) * 4;
    float* d = dst0 + e * 64 + b;
    d[0] = acc[i].x; d[64] = acc[i].y; d[128] = acc[i].z; d[192] = acc[i].w;
  }
}

// Persistent encoder: WGs 0..127 layer0 step t, WGs 128..255 layer1 step t-1.
__global__ __launch_bounds__(256) void k_enc_persist(
    const float* __restrict__ xT, float* h1buf, float* h2buf,
    const float* __restrict__ Wih0, const float* __restrict__ Whh0,
    const float* __restrict__ bih0, const float* __restrict__ bhh0,
    const float* __restrict__ Wih1, const float* __restrict__ Whh1,
    const float* __restrict__ bih1, const float* __restrict__ bhh1,
    unsigned* ebase, unsigned* dbase) {
  int wg = blockIdx.x, tid = threadIdx.x;
  int s = tid >> 6, b = tid & 63;
  unsigned* eflags = ebase;
  unsigned* ego = ebase + 256;
  for (int t = 0; t <= TT; ++t) {
    const float* h1_r = h1buf + (t & 1) * (HH * BB);        // h1[t-1]
    float* h1_w = h1buf + ((t + 1) & 1) * (HH * BB);        // h1[t]
    if (wg < 128) {
      if (t < TT) {
        int j = wg * 4 + s;
        float ar, az, an, hr, hz, hn;
        dot3_kb<EE>(xT + (size_t)t * (EE * 64), b,
                    Wih0 + (size_t)j * EE, Wih0 + (size_t)(512 + j) * EE,
                    Wih0 + (size_t)(1024 + j) * EE, ar, az, an);
        dot3_kb_a<HH>(h1_r, b,
                      Whh0 + (size_t)j * HH, Whh0 + (size_t)(512 + j) * HH,
                      Whh0 + (size_t)(1024 + j) * HH, hr, hz, hn);
        float r = sigm((ar + bih0[j]) + (hr + bhh0[j]));
        float z = sigm((az + bih0[512 + j]) + (hz + bhh0[512 + j]));
        float n = tanhf((an + bih0[1024 + j]) + r * (hn + bhh0[1024 + j]));
        stf_a(&h1_w[j * 64 + b],
              (1.0f - z) * n + z * ldf_a(&h1_r[j * 64 + b]));
      }
    } else {
      if (t >= 1) {  // layer1 processes step t-1
        int j = (wg - 128) * 4 + s;
        const float* h2_r = h2buf + ((t + 1) & 1) * (HH * BB);  // h2[t-2]
        float* h2_w = h2buf + (t & 1) * (HH * BB);              // h2[t-1]
        float ar, az, an, hr, hz, hn;
        dot3_kb_a<HH>(h1_r, b,   // input = seq1[t-1] = h1[t-1]
                      Wih1 + (size_t)j * HH, Wih1 + (size_t)(512 + j) * HH,
                      Wih1 + (size_t)(1024 + j) * HH, ar, az, an);
        dot3_kb_a<HH>(h2_r, b,
                      Whh1 + (size_t)j * HH, Whh1 + (size_t)(512 + j) * HH,
                      Whh1 + (size_t)(1024 + j) * HH, hr, hz, hn);
        float r = sigm((ar + bih1[j]) + (hr + bhh1[j]));
        float z = sigm((az + bih1[512 + j]) + (hz + bhh1[512 + j]));
        float n = tanhf((an + bih1[1024 + j]) + r * (hn + bhh1[1024 + j]));
        stf_a(&h2_w[j * 64 + b],
              (1.0f - z) * n + z * ldf_a(&h2_r[j * 64 + b]));
      }
    }
    // Zero the decoder's barrier words (overlay xT[0..255], whose only
    // reads were at t=0; by t==2 every WG passed flagbar(1) -> reads done).
    if (t == 2 && wg == 0) stu_a(dbase + tid, 0u);
    if (t < TT) flagbar<256>(eflags, ego, wg, (unsigned)(t + 1));
    // t==TT iteration needs no barrier: kernel end is the sync.
  }
}

// Persistent decoder, 128 WGs, 5 phases/step, fenceless barriers.
__global__ __launch_bounds__(256) void k_dec_persist(
    float* h1buf, float* h2buf,
    const float* __restrict__ demb,
    const float* __restrict__ dWih0, const float* __restrict__ dWhh0,
    const float* __restrict__ dbih0, const float* __restrict__ dbhh0,
    const float* __restrict__ dWih1, const float* __restrict__ dWhh1,
    const float* __restrict__ dbih1, const float* __restrict__ dbhh1,
    const float* __restrict__ Wp1, const float* __restrict__ bp1,
    const float* __restrict__ Wp2, const float* __restrict__ bp2,
    float* out, int* tok, unsigned* dbase, float* hid, float* lg) {
  int wg = blockIdx.x, tid = threadIdx.x;
  int s = tid >> 6, b = tid & 63;
  unsigned* dflags = dbase;
  unsigned* dgo = dbase + 128;
  __shared__ float rf[8];
  __shared__ int ri[4];
  unsigned rk0 = 0u, rk1 = 42u;  // jax.random.key(42); chain kept in regs
  unsigned ep = 0u;
  for (int d = 0; d < TT - 1; ++d) {
    // -------- phase A: decoder layer0 (128 WGs, feature-parallel) --------
    {
      const float* h1_r = h1buf + (d & 1) * (HH * BB);
      float* h1_w = h1buf + ((d + 1) & 1) * (HH * BB);
      int j = wg * 4 + s;
      int tk = (int)ldu_a((const unsigned*)&tok[b]);
      float ar, az, an, hr, hz, hn;
      dot3_row<EE>(demb + (size_t)tk * EE,
                   dWih0 + (size_t)j * EE, dWih0 + (size_t)(512 + j) * EE,
                   dWih0 + (size_t)(1024 + j) * EE, ar, az, an);
      dot3_kb_a<HH>(h1_r, b,
                    dWhh0 + (size_t)j * HH, dWhh0 + (size_t)(512 + j) * HH,
                    dWhh0 + (size_t)(1024 + j) * HH, hr, hz, hn);
      float r = sigm((ar + dbih0[j]) + (hr + dbhh0[j]));
      float z = sigm((az + dbih0[512 + j]) + (hz + dbhh0[512 + j]));
      float n = tanhf((an + dbih0[1024 + j]) + r * (hn + dbhh0[1024 + j]));
      stf_a(&h1_w[j * 64 + b],
            (1.0f - z) * n + z * ldf_a(&h1_r[j * 64 + b]));
    }
    flagbar<128>(dflags, dgo, wg, ++ep);
    // -------- phase B: decoder layer1 (128 WGs) --------
    {
      const float* h1n = h1buf + ((d + 1) & 1) * (HH * BB);
      const float* h2r = h2buf + (d & 1) * (HH * BB);
      float* h2w = h2buf + ((d + 1) & 1) * (HH * BB);
      int j = wg * 4 + s;
      float ar, az, an, hr, hz, hn;
      dot3_kb_a<HH>(h1n, b,
                    dWih1 + (size_t)j * HH, dWih1 + (size_t)(512 + j) * HH,
                    dWih1 + (size_t)(1024 + j) * HH, ar, az, an);
      dot3_kb_a<HH>(h2r, b,
                    dWhh1 + (size_t)j * HH, dWhh1 + (size_t)(512 + j) * HH,
                    dWhh1 + (size_t)(1024 + j) * HH, hr, hz, hn);
      float r = sigm((ar + dbih1[j]) + (hr + dbhh1[j]));
      float z = sigm((az + dbih1[512 + j]) + (hz + dbhh1[512 + j]));
      float n = tanhf((an + dbih1[1024 + j]) + r * (hn + dbhh1[1024 + j]));
      stf_a(&h2w[j * 64 + b],
            (1.0f - z) * n + z * ldf_a(&h2r[j * 64 + b]));
    }
    flagbar<128>(dflags, dgo, wg, ++ep);
    // -------- phase C1: hid[j][b] = LeakyReLU(Wp1 row j . h2') --------
    {
      const float* h2n = h2buf + ((d + 1) & 1) * (HH * BB);
      int j = wg * 4 + s;
      float a = dot1_kb_a<HH>(h2n, b, Wp1 + (size_t)j * HH);
      a += bp1[j];
      stf_a(&hid[j * 64 + b], (a >= 0.f) ? a : 0.1f * a);
    }
    flagbar<128>(dflags, dgo, wg, ++ep);
    // -------- phase C2: lg[c][b] = Wp2 row c . hid + bp2[c] --------
    {
      int c = wg * 4 + s;
      if (c < VV) {
        float a = dot1_kb_a<HH>(hid, b, Wp2 + (size_t)c * HH);
        stf_a(&lg[c * 64 + b], a + bp2[c]);
      }
    }
    flagbar<128>(dflags, dgo, wg, ++ep);
    // -------- phase C3: max/gumbel/softmax per batch row (WGs 0..63) -----
    if (wg < BB) {
      int brow = wg;
      float v0 = (tid < VV) ? ldf_a(lg + (size_t)tid * 64 + brow) : 0.f;
      float v1 = (tid + 256 < VV) ? ldf_a(lg + (size_t)(tid + 256) * 64 + brow) : 0.f;
      // row max (same reduction order as verified kernel)
      float m = -INFINITY;
      if (tid < VV) m = fmaxf(m, v0);
      if (tid + 256 < VV) m = fmaxf(m, v1);
      for (int off = 32; off > 0; off >>= 1) m = fmaxf(m, __shfl_down(m, off, 64));
      if ((tid & 63) == 0) rf[tid >> 6] = m;
      __syncthreads();
      if (tid == 0) rf[4] = fmaxf(fmaxf(rf[0], rf[1]), fmaxf(rf[2], rf[3]));
      __syncthreads();
      m = rf[4];
      // sk = TF(rng_d, (0,1)); gumbel-argmax (first-index ties)
      unsigned sk0, sk1;
      tf2x32(rk0, rk1, 0u, 1u, sk0, sk1);
      float by = -INFINITY; int bc = 0x7fffffff;
      if (tid < VV) {
        unsigned o0, o1;
        tf2x32(sk0, sk1, 0u, (unsigned)(brow * VV + tid), o0, o1);
        unsigned bits = o0 ^ o1;
        float f = __uint_as_float(0x3f800000u | (bits >> 9)) - 1.0f;
        float u = (f > 0.f) ? f : 1.17549435e-38f;
        float g = (float)(-log(-log((double)u)));
        float y = v0 + g;
        if (y > by || (y == by && tid < bc)) { by = y; bc = tid; }
      }
      if (tid + 256 < VV) {
        int c = tid + 256;
        unsigned o0, o1;
        tf2x32(sk0, sk1, 0u, (unsigned)(brow * VV + c), o0, o1);
        unsigned bits = o0 ^ o1;
        float f = __uint_as_float(0x3f800000u | (bits >> 9)) - 1.0f;
        float u = (f > 0.f) ? f : 1.17549435e-38f;
        float g = (float)(-log(-log((double)u)));
        float y = v1 + g;
        if (y > by || (y == by && c < bc)) { by = y; bc = c; }
      }
      for (int off = 32; off > 0; off >>= 1) {
        float oy = __shfl_down(by, off, 64);
        int oc = __shfl_down(bc, off, 64);
        if (oy > by || (oy == by && oc < bc)) { by = oy; bc = oc; }
      }
      if ((tid & 63) == 0) { rf[tid >> 6] = by; ri[tid >> 6] = bc; }
      __syncthreads();
      if (tid == 0) {
        by = rf[0]; bc = ri[0];
        for (int w2 = 1; w2 < 4; ++w2)
          if (rf[w2] > by || (rf[w2] == by && ri[w2] < bc)) { by = rf[w2]; bc = ri[w2]; }
        stu_a((unsigned*)&tok[brow], (unsigned)bc);
        out[(size_t)BB * TT * VV + (size_t)brow * TT + (d + 1)] = (float)bc;
      }
      __syncthreads();
      // softmax probs (plain out writes; host reads after kernel end)
      float e0 = 0.f, e1 = 0.f, ssum = 0.f;
      if (tid < VV) { e0 = expf(v0 - m); ssum += e0; }
      if (tid + 256 < VV) { e1 = expf(v1 - m); ssum += e1; }
      for (int off = 32; off > 0; off >>= 1) ssum += __shfl_down(ssum, off, 64);
      if ((tid & 63) == 0) rf[tid >> 6] = ssum;
      __syncthreads();
      if (tid == 0) rf[4] = (rf[0] + rf[1]) + (rf[2] + rf[3]);
      __syncthreads();
      float S = rf[4];
      float* orow = out + ((size_t)brow * TT + (d + 1)) * VV;
      if (tid < VV) orow[tid] = e0 / S;
      if (tid + 256 < VV) orow[tid + 256] = e1 / S;
    }
    // every WG advances the key chain identically: rng_{d+1}=TF(rng_d,(0,0))
    {
      unsigned n0, n1;
      tf2x32(rk0, rk1, 0u, 0u, n0, n1);
      rk0 = n0; rk1 = n1;
    }
    if (d < TT - 2) flagbar<128>(dflags, dgo, wg, ++ep);
  }
}

extern "C" void kernel_launch(void* const* d_in, const int* in_sizes, int n_in,
                              void* d_out, int out_size, void* d_ws, size_t ws_size,
                              hipStream_t stream) {
  (void)in_sizes; (void)n_in; (void)out_size; (void)ws_size;
  const float* input = (const float*)d_in[0];
  const float* e_emb = (const float*)d_in[1];
  const float* eWih0 = (const float*)d_in[2];
  const float* eWhh0 = (const float*)d_in[3];
  const float* ebih0 = (const float*)d_in[4];
  const float* ebhh0 = (const float*)d_in[5];
  const float* eWih1 = (const float*)d_in[6];
  const float* eWhh1 = (const float*)d_in[7];
  const float* ebih1 = (const float*)d_in[8];
  const float* ebhh1 = (const float*)d_in[9];
  const float* d_emb = (const float*)d_in[10];
  const float* dWih0 = (const float*)d_in[11];
  const float* dWhh0 = (const float*)d_in[12];
  const float* dbih0 = (const float*)d_in[13];
  const float* dbhh0 = (const float*)d_in[14];
  const float* dWih1 = (const float*)d_in[15];
  const float* dWhh1 = (const float*)d_in[16];
  const float* dbih1 = (const float*)d_in[17];
  const float* dbhh1 = (const float*)d_in[18];
  const float* Wp1   = (const float*)d_in[19];
  const float* bp1   = (const float*)d_in[20];
  const float* Wp2   = (const float*)d_in[21];
  const float* bp2   = (const float*)d_in[22];
  float* out = (float*)d_out;

  // ws layout (unchanged): xT [512][256][64] | h1 ping-pong | h2 ping-pong | tok
  float* xT = (float*)d_ws;
  float* h1buf = xT + (size_t)TT * EE * 64;
  float* h2buf = h1buf + 2 * HH * BB;
  int* tok = (int*)(h2buf + 2 * HH * BB);
  // Overlays on dead storage:
  //  - ebase: out probs rows (b=1, t=1..) -- dead until decoder d=0 phase C3
  //    (which runs after the encoder kernel completed). 512 uints.
  //  - dbase: xT[0..255] -- xT's t=0 block is only read at encoder t=0;
  //    zeroed inside k_enc_persist at t==2. dflags[128] | dgo[128].
  //  - hid/lg: xT+4096.. -- xT fully dead during the decoder.
  unsigned* ebase = (unsigned*)(out + ((size_t)1 * TT + 1) * VV);
  unsigned* dbase = (unsigned*)xT;
  float* hid = xT + 4096;
  float* lg  = hid + (size_t)HH * BB;

  k_init<<<64, 256, 0, stream>>>(out, h1buf, h2buf, tok, ebase);
  k_xgemm<<<TT, 256, 0, stream>>>(input, e_emb, xT);
  k_enc_persist<<<256, 256, 0, stream>>>(xT, h1buf, h2buf,
      eWih0, eWhh0, ebih0, ebhh0, eWih1, eWhh1, ebih1, ebhh1, ebase, dbase);
  k_dec_persist<<<128, 256, 0, stream>>>(h1buf, h2buf, d_emb,
      dWih0, dWhh0, dbih0, dbhh0, dWih1, dWhh1, dbih1, dbhh1,
      Wp1, bp1, Wp2, bp2, out, tok, dbase, hid, lg);
}

// Round 3
// 74878.162 us; speedup vs baseline: 1.6313x; 1.1251x over previous
//
#include <hip/hip_runtime.h>
#include <math.h>

// Seq2seq GRU encoder/decoder with exact JAX threefry sampling.
// R4 design: persistent + fenceless sc1 barriers (R3-proven) + latency fixes:
//   - R2 post-mortem: 30us per phase+barrier unit. sc1 X-loads (L3 ~600cy)
//     were serialized by unroll-4 basic blocks (no cross-BB load hoisting),
//     at 1 wave/SIMD. Barrier had 3 L3 hops (flag->master->go->spinner).
//   - Fixes: FULL unroll of all dots (one BB -> scheduler hoists ~50 loads
//     deep); state swizzled [k/4][b][4] so X loads are 8B (2/k4 not 4);
//     ih/hh dots split onto separate waves (LDS-combined, exact same
//     combine expression); encoder 512 WGs = 2/CU = 2 waves/SIMD TLP;
//     direct all-poll barrier (1 hop); C2+C3 fused (logits from LDS hid,
//     same dot order).
//   - Every fma chain keeps the EXACT R2 op order -> bit-identical output
//     (absmax must stay exactly 1.525879e-05; deviation = swizzle bug).

#define BB 64
#define TT 512
#define VV 390
#define EE 256
#define HH 512

// swizzled state layout: elem (k, b) at [(k>>2)*256 + b*4 + (k&3)]
#define SW(k, b) ((((k) >> 2) << 8) + ((b) << 2) + ((k) & 3))

static __device__ __forceinline__ void tf2x32(unsigned k0, unsigned k1,
                                              unsigned x0, unsigned x1,
                                              unsigned &o0, unsigned &o1) {
  unsigned ks2 = k0 ^ k1 ^ 0x1BD11BDAu;
  x0 += k0; x1 += k1;
#define TFR(r) x0 += x1; x1 = (x1 << (r)) | (x1 >> (32 - (r))); x1 ^= x0;
  TFR(13) TFR(15) TFR(26) TFR(6)
  x0 += k1; x1 += ks2 + 1u;
  TFR(17) TFR(29) TFR(16) TFR(24)
  x0 += ks2; x1 += k0 + 2u;
  TFR(13) TFR(15) TFR(26) TFR(6)
  x0 += k0; x1 += k1 + 3u;
  TFR(17) TFR(29) TFR(16) TFR(24)
  x0 += k1; x1 += ks2 + 4u;
  TFR(13) TFR(15) TFR(26) TFR(6)
  x0 += ks2; x1 += k0 + 5u;
#undef TFR
  o0 = x0; o1 = x1;
}

static __device__ __forceinline__ float sigm(float x) {
  return 1.0f / (1.0f + expf(-x));
}

// ---- agent-scope relaxed (sc1) helpers: coherent at L3, no fences ----
static __device__ __forceinline__ unsigned ldu_a(const unsigned* p) {
  return __hip_atomic_load((unsigned*)p, __ATOMIC_RELAXED,
                           __HIP_MEMORY_SCOPE_AGENT);
}
static __device__ __forceinline__ void stu_a(unsigned* p, unsigned v) {
  __hip_atomic_store(p, v, __ATOMIC_RELAXED, __HIP_MEMORY_SCOPE_AGENT);
}
static __device__ __forceinline__ float ldf_a(const float* p) {
  return __uint_as_float(ldu_a((const unsigned*)p));
}
static __device__ __forceinline__ void stf_a(float* p, float v) {
  stu_a((unsigned*)p, __float_as_uint(v));
}
static __device__ __forceinline__ float2 ldf2_a(const float* p) {
  unsigned long long v = __hip_atomic_load((unsigned long long*)p,
      __ATOMIC_RELAXED, __HIP_MEMORY_SCOPE_AGENT);
  return make_float2(__uint_as_float((unsigned)v),
                     __uint_as_float((unsigned)(v >> 32)));
}

// 3-row dot over SWIZZLED sc1 state X, K floats. Full unroll: single BB so
// the scheduler hoists the sc1 loads deep. fma order identical to R2's
// dot3_kb_a (per k4: s0 x0..x3, s1 x0..x3, s2 x0..x3).
template <int K>
static __device__ __forceinline__ void dot3s_a(const float* __restrict__ X, int b,
    const float* __restrict__ w0, const float* __restrict__ w1,
    const float* __restrict__ w2, float &r0, float &r1, float &r2) {
  const float4* q0 = (const float4*)w0;
  const float4* q1 = (const float4*)w1;
  const float4* q2 = (const float4*)w2;
  const float* Xb = X + (b << 2);
  float s0 = 0.f, s1 = 0.f, s2 = 0.f;
#pragma unroll
  for (int k4 = 0; k4 < (K >> 2); ++k4) {
    float2 xa = ldf2_a(Xb + (k4 << 8));
    float2 xc = ldf2_a(Xb + (k4 << 8) + 2);
    float4 u0 = q0[k4], u1 = q1[k4], u2 = q2[k4];
    s0 = fmaf(xa.x, u0.x, s0); s0 = fmaf(xa.y, u0.y, s0); s0 = fmaf(xc.x, u0.z, s0); s0 = fmaf(xc.y, u0.w, s0);
    s1 = fmaf(xa.x, u1.x, s1); s1 = fmaf(xa.y, u1.y, s1); s1 = fmaf(xc.x, u1.z, s1); s1 = fmaf(xc.y, u1.w, s1);
    s2 = fmaf(xa.x, u2.x, s2); s2 = fmaf(xa.y, u2.y, s2); s2 = fmaf(xc.x, u2.z, s2); s2 = fmaf(xc.y, u2.w, s2);
  }
  r0 = s0; r1 = s1; r2 = s2;
}

// Single-row variant (Wp1 phase).
template <int K>
static __device__ __forceinline__ float dot1s_a(const float* __restrict__ X, int b,
    const float* __restrict__ w) {
  const float4* q = (const float4*)w;
  const float* Xb = X + (b << 2);
  float s = 0.f;
#pragma unroll
  for (int k4 = 0; k4 < (K >> 2); ++k4) {
    float2 xa = ldf2_a(Xb + (k4 << 8));
    float2 xc = ldf2_a(Xb + (k4 << 8) + 2);
    float4 u = q[k4];
    s = fmaf(xa.x, u.x, s); s = fmaf(xa.y, u.y, s);
    s = fmaf(xc.x, u.z, s); s = fmaf(xc.y, u.w, s);
  }
  return s;
}

// 3-row dot over SWIZZLED read-only X (plain cached loads) — encoder xT.
template <int K>
static __device__ __forceinline__ void dot3s_p(const float* __restrict__ X, int b,
    const float* __restrict__ w0, const float* __restrict__ w1,
    const float* __restrict__ w2, float &r0, float &r1, float &r2) {
  const float4* q0 = (const float4*)w0;
  const float4* q1 = (const float4*)w1;
  const float4* q2 = (const float4*)w2;
  const float4* Xp = (const float4*)X;
  float s0 = 0.f, s1 = 0.f, s2 = 0.f;
#pragma unroll
  for (int k4 = 0; k4 < (K >> 2); ++k4) {
    float4 x = Xp[(k4 << 6) + b];
    float4 u0 = q0[k4], u1 = q1[k4], u2 = q2[k4];
    s0 = fmaf(x.x, u0.x, s0); s0 = fmaf(x.y, u0.y, s0); s0 = fmaf(x.z, u0.z, s0); s0 = fmaf(x.w, u0.w, s0);
    s1 = fmaf(x.x, u1.x, s1); s1 = fmaf(x.y, u1.y, s1); s1 = fmaf(x.z, u1.z, s1); s1 = fmaf(x.w, u1.w, s1);
    s2 = fmaf(x.x, u2.x, s2); s2 = fmaf(x.y, u2.y, s2); s2 = fmaf(x.z, u2.z, s2); s2 = fmaf(x.w, u2.w, s2);
  }
  r0 = s0; r1 = s1; r2 = s2;
}

// Per-lane contiguous row (embedding gather, read-only) — unchanged order.
template <int K>
static __device__ __forceinline__ void dot3_row(const float* __restrict__ xrow,
    const float* __restrict__ w0, const float* __restrict__ w1,
    const float* __restrict__ w2, float &r0, float &r1, float &r2) {
  const float4* xq = (const float4*)xrow;
  const float4* q0 = (const float4*)w0;
  const float4* q1 = (const float4*)w1;
  const float4* q2 = (const float4*)w2;
  float s0 = 0.f, s1 = 0.f, s2 = 0.f;
#pragma unroll
  for (int k4 = 0; k4 < (K >> 2); ++k4) {
    float4 x = xq[k4];
    float4 u0 = q0[k4], u1 = q1[k4], u2 = q2[k4];
    s0 = fmaf(x.x, u0.x, s0); s0 = fmaf(x.y, u0.y, s0); s0 = fmaf(x.z, u0.z, s0); s0 = fmaf(x.w, u0.w, s0);
    s1 = fmaf(x.x, u1.x, s1); s1 = fmaf(x.y, u1.y, s1); s1 = fmaf(x.z, u1.z, s1); s1 = fmaf(x.w, u1.w, s1);
    s2 = fmaf(x.x, u2.x, s2); s2 = fmaf(x.y, u2.y, s2); s2 = fmaf(x.z, u2.z, s2); s2 = fmaf(x.w, u2.w, s2);
  }
  r0 = s0; r1 = s1; r2 = s2;
}

// Direct all-poll grid barrier: flag store + wave0 polls all flags.
// Entry __syncthreads() drains vmcnt -> this WG's sc1 stores are at the
// coherent point before its flag publishes them. One L3 hop.
template <int NWG>
static __device__ __forceinline__ void bar(unsigned* flags, int wg, unsigned ep) {
  __syncthreads();
  int tid = threadIdx.x;
  if (tid == 0) stu_a(flags + wg, ep);
  if (tid < 64) {
    bool ok;
    do {
      ok = true;
#pragma unroll
      for (int i = 0; i < NWG; i += 64)
        ok &= (ldu_a(flags + i + tid) >= ep);
    } while (!__all(ok));
  }
  __syncthreads();
}

__global__ __launch_bounds__(256) void k_init(float* out,
    float* h1buf, float* h2buf, int* tok, unsigned* ebase) {
  int wg = blockIdx.x, tid = threadIdx.x;
  for (int i = wg * 256 + tid; i < HH * BB; i += 64 * 256) {
    h1buf[i] = 0.f;  // slot 0 only (slot 1 always written before read)
    h2buf[i] = 0.f;
  }
  for (int v = tid; v < VV; v += 256)
    out[(size_t)wg * TT * VV + v] = (v == 388) ? 1.0f : 0.0f;
  if (wg == 0) {  // encoder flags: 512 words
    ebase[tid] = 0u;
    ebase[tid + 256] = 0u;
  }
  if (tid == 0) {
    out[(size_t)BB * TT * VV + (size_t)wg * TT] = 388.0f;
    tok[wg] = 388;
  }
}

// x_swz[t][(e>>2)*256 + b*4 + (e&3)] = sum_v input[b][t][v]*emb[v][e].
__global__ __launch_bounds__(256) void k_xgemm(const float* __restrict__ input,
    const float* __restrict__ emb, float* __restrict__ xT) {
  int t = blockIdx.x, tid = threadIdx.x;
  int s = tid >> 6, b = tid & 63;
  __shared__ float lin[64 * 65];
  float4 acc[16];
#pragma unroll
  for (int i = 0; i < 16; ++i) acc[i] = make_float4(0.f, 0.f, 0.f, 0.f);
  for (int k0 = 0; k0 < VV; k0 += 64) {
    int kmax = min(64, VV - k0);
    __syncthreads();
#pragma unroll
    for (int r = 0; r < 16; ++r) {
      int idx = r * 256 + tid;
      int b2 = idx >> 6, kk = idx & 63;
      if (kk < kmax)
        lin[kk * 65 + b2] = input[((size_t)b2 * TT + t) * VV + k0 + kk];
    }
    __syncthreads();
    for (int kk = 0; kk < kmax; ++kk) {
      float xv = lin[kk * 65 + b];
      const float4* er = (const float4*)(emb + (size_t)(k0 + kk) * EE);
#pragma unroll
      for (int i = 0; i < 16; ++i) {
        float4 w = er[s + 4 * i];
        acc[i].x = fmaf(xv, w.x, acc[i].x);
        acc[i].y = fmaf(xv, w.y, acc[i].y);
        acc[i].z = fmaf(xv, w.z, acc[i].z);
        acc[i].w = fmaf(xv, w.w, acc[i].w);
      }
    }
  }
  float* dst0 = xT + (size_t)t * (EE * 64);
#pragma unroll
  for (int i = 0; i < 16; ++i) {
    // e-group = s+4i, lane b -> float4 store at [(e>>2)*256 + 4b], coalesced
    *(float4*)(dst0 + (s + 4 * i) * 256 + 4 * b) = acc[i];
  }
}

// Persistent encoder: 512 WGs, 2/CU. WGs 0..255 layer0 step t, 256..511
// layer1 step t-1. Per WG: 2 columns (cs=s&1), task (s>>1): 0=ih-dot +
// finalize, 1=hh-dot -> LDS.
__global__ __launch_bounds__(256, 2) void k_enc(
    const float* __restrict__ xT, float* h1buf, float* h2buf,
    const float* __restrict__ Wih0, const float* __restrict__ Whh0,
    const float* __restrict__ bih0, const float* __restrict__ bhh0,
    const float* __restrict__ Wih1, const float* __restrict__ Whh1,
    const float* __restrict__ bih1, const float* __restrict__ bhh1,
    unsigned* eflags, unsigned* dbase) {
  int wg = blockIdx.x, tid = threadIdx.x;
  int s = tid >> 6, b = tid & 63;
  int cs = s & 1, task = s >> 1;
  bool lay1 = (wg >= 256);
  int j = (lay1 ? (wg - 256) : wg) * 2 + cs;
  __shared__ float part[2][3][64];
  for (int t = 0; t <= TT; ++t) {
    const float* h1_r = h1buf + (t & 1) * (HH * BB);        // h1[t-1]
    float* h1_w = h1buf + ((t + 1) & 1) * (HH * BB);        // h1[t]
    bool active = lay1 ? (t >= 1) : (t < TT);
    float ar = 0.f, az = 0.f, an = 0.f;
    if (active) {
      if (!lay1) {
        if (task == 0) {
          dot3s_p<EE>(xT + (size_t)t * (EE * 64), b,
                      Wih0 + (size_t)j * EE, Wih0 + (size_t)(512 + j) * EE,
                      Wih0 + (size_t)(1024 + j) * EE, ar, az, an);
        } else {
          float hr, hz, hn;
          dot3s_a<HH>(h1_r, b,
                      Whh0 + (size_t)j * HH, Whh0 + (size_t)(512 + j) * HH,
                      Whh0 + (size_t)(1024 + j) * HH, hr, hz, hn);
          part[cs][0][b] = hr; part[cs][1][b] = hz; part[cs][2][b] = hn;
        }
      } else {
        if (task == 0) {
          dot3s_a<HH>(h1_r, b,   // input = seq1[t-1] = h1[t-1]
                      Wih1 + (size_t)j * HH, Wih1 + (size_t)(512 + j) * HH,
                      Wih1 + (size_t)(1024 + j) * HH, ar, az, an);
        } else {
          const float* h2_r = h2buf + ((t + 1) & 1) * (HH * BB);  // h2[t-2]
          float hr, hz, hn;
          dot3s_a<HH>(h2_r, b,
                      Whh1 + (size_t)j * HH, Whh1 + (size_t)(512 + j) * HH,
                      Whh1 + (size_t)(1024 + j) * HH, hr, hz, hn);
          part[cs][0][b] = hr; part[cs][1][b] = hz; part[cs][2][b] = hn;
        }
      }
    }
    __syncthreads();
    if (active && task == 0) {
      float hr = part[cs][0][b], hz = part[cs][1][b], hn = part[cs][2][b];
      if (!lay1) {
        float r = sigm((ar + bih0[j]) + (hr + bhh0[j]));
        float z = sigm((az + bih0[512 + j]) + (hz + bhh0[512 + j]));
        float n = tanhf((an + bih0[1024 + j]) + r * (hn + bhh0[1024 + j]));
        float hp = ldf_a(h1_r + SW(j, b));
        stf_a(h1_w + SW(j, b), (1.0f - z) * n + z * hp);
      } else {
        const float* h2_r = h2buf + ((t + 1) & 1) * (HH * BB);
        float* h2_w = h2buf + (t & 1) * (HH * BB);
        float r = sigm((ar + bih1[j]) + (hr + bhh1[j]));
        float z = sigm((az + bih1[512 + j]) + (hz + bhh1[512 + j]));
        float n = tanhf((an + bih1[1024 + j]) + r * (hn + bhh1[1024 + j]));
        float hp = ldf_a(h2_r + SW(j, b));
        stf_a(h2_w + SW(j, b), (1.0f - z) * n + z * hp);
      }
    }
    // Zero decoder flags (overlay xT[0..255]; its only reads were t=0,
    // and every WG has passed the t=1 barrier by now).
    if (t == 2 && wg == 0 && tid < 64) {
#pragma unroll
      for (int i = 0; i < 256; i += 64) stu_a(dbase + i + tid, 0u);
    }
    if (t < TT) bar<512>(eflags, wg, (unsigned)(t + 1));
  }
}

// Persistent decoder: 256 WGs, 4 phases/step. Phases A/B/C1: 2 cols/WG,
// ih/hh dot-tasks on separate waves. C23: 64 row-WGs, hid staged in LDS.
__global__ __launch_bounds__(256) void k_dec(
    float* h1buf, float* h2buf,
    const float* __restrict__ demb,
    const float* __restrict__ dWih0, const float* __restrict__ dWhh0,
    const float* __restrict__ dbih0, const float* __restrict__ dbhh0,
    const float* __restrict__ dWih1, const float* __restrict__ dWhh1,
    const float* __restrict__ dbih1, const float* __restrict__ dbhh1,
    const float* __restrict__ Wp1, const float* __restrict__ bp1,
    const float* __restrict__ Wp2, const float* __restrict__ bp2,
    float* out, int* tok, unsigned* dflags, float* hid) {
  int wg = blockIdx.x, tid = threadIdx.x;
  int s = tid >> 6, b = tid & 63;
  int cs = s & 1, task = s >> 1;
  int j = wg * 2 + cs;
  __shared__ float part[2][3][64];
  __shared__ __align__(16) float lhid[HH];
  __shared__ float rf[8];
  __shared__ int ri[4];
  unsigned rk0 = 0u, rk1 = 42u;  // jax.random.key(42), chained in registers
  unsigned ep = 0u;
  for (int d = 0; d < TT - 1; ++d) {
    const float* h1_r = h1buf + (d & 1) * (HH * BB);
    float* h1_w = h1buf + ((d + 1) & 1) * (HH * BB);
    const float* h2_r = h2buf + (d & 1) * (HH * BB);
    float* h2_w = h2buf + ((d + 1) & 1) * (HH * BB);
    // ---------------- phase A: decoder layer0 ----------------
    {
      float ar = 0.f, az = 0.f, an = 0.f;
      if (task == 1) {
        float hr, hz, hn;
        dot3s_a<HH>(h1_r, b,
                    dWhh0 + (size_t)j * HH, dWhh0 + (size_t)(512 + j) * HH,
                    dWhh0 + (size_t)(1024 + j) * HH, hr, hz, hn);
        part[cs][0][b] = hr; part[cs][1][b] = hz; part[cs][2][b] = hn;
      } else {
        int tk = (int)ldu_a((const unsigned*)tok + b);
        dot3_row<EE>(demb + (size_t)tk * EE,
                     dWih0 + (size_t)j * EE, dWih0 + (size_t)(512 + j) * EE,
                     dWih0 + (size_t)(1024 + j) * EE, ar, az, an);
      }
      __syncthreads();
      if (task == 0) {
        float hr = part[cs][0][b], hz = part[cs][1][b], hn = part[cs][2][b];
        float r = sigm((ar + dbih0[j]) + (hr + dbhh0[j]));
        float z = sigm((az + dbih0[512 + j]) + (hz + dbhh0[512 + j]));
        float n = tanhf((an + dbih0[1024 + j]) + r * (hn + dbhh0[1024 + j]));
        float hp = ldf_a(h1_r + SW(j, b));
        stf_a(h1_w + SW(j, b), (1.0f - z) * n + z * hp);
      }
    }
    bar<256>(dflags, wg, ++ep);
    // ---------------- phase B: decoder layer1 ----------------
    {
      float ar = 0.f, az = 0.f, an = 0.f;
      if (task == 1) {
        float hr, hz, hn;
        dot3s_a<HH>(h2_r, b,
                    dWhh1 + (size_t)j * HH, dWhh1 + (size_t)(512 + j) * HH,
                    dWhh1 + (size_t)(1024 + j) * HH, hr, hz, hn);
        part[cs][0][b] = hr; part[cs][1][b] = hz; part[cs][2][b] = hn;
      } else {
        dot3s_a<HH>(h1_w, b,  // h1' written in phase A
                    dWih1 + (size_t)j * HH, dWih1 + (size_t)(512 + j) * HH,
                    dWih1 + (size_t)(1024 + j) * HH, ar, az, an);
      }
      __syncthreads();
      if (task == 0) {
        float hr = part[cs][0][b], hz = part[cs][1][b], hn = part[cs][2][b];
        float r = sigm((ar + dbih1[j]) + (hr + dbhh1[j]));
        float z = sigm((az + dbih1[512 + j]) + (hz + dbhh1[512 + j]));
        float n = tanhf((an + dbih1[1024 + j]) + r * (hn + dbhh1[1024 + j]));
        float hp = ldf_a(h2_r + SW(j, b));
        stf_a(h2_w + SW(j, b), (1.0f - z) * n + z * hp);
      }
    }
    bar<256>(dflags, wg, ++ep);
    // ---------------- phase C1: hid = LeakyReLU(Wp1 . h2') ----------------
    if (task == 0) {
      float a = dot1s_a<HH>(h2_w, b, Wp1 + (size_t)j * HH);
      a += bp1[j];
      stf_a(hid + SW(j, b), (a >= 0.f) ? a : 0.1f * a);
    }
    bar<256>(dflags, wg, ++ep);
    // -------- phase C23: logits + max/gumbel/softmax (WGs 0..63) --------
    if (wg < BB) {
      int brow = wg;
      if (tid < 128) {  // stage hid[:,brow] -> lhid (512 floats)
        float2 ha = ldf2_a(hid + tid * 256 + brow * 4);
        float2 hb = ldf2_a(hid + tid * 256 + brow * 4 + 2);
        lhid[4 * tid] = ha.x; lhid[4 * tid + 1] = ha.y;
        lhid[4 * tid + 2] = hb.x; lhid[4 * tid + 3] = hb.y;
      }
      __syncthreads();
      float v0 = 0.f, v1 = 0.f;
      if (tid < VV) {
        const float4* w = (const float4*)(Wp2 + (size_t)tid * HH);
        float a = 0.f;
#pragma unroll 8
        for (int k4 = 0; k4 < HH / 4; ++k4) {
          float4 q = w[k4];
          float4 hv = *(const float4*)&lhid[k4 * 4];
          a = fmaf(hv.x, q.x, a); a = fmaf(hv.y, q.y, a);
          a = fmaf(hv.z, q.z, a); a = fmaf(hv.w, q.w, a);
        }
        v0 = a + bp2[tid];
      }
      if (tid + 256 < VV) {
        const float4* w = (const float4*)(Wp2 + (size_t)(tid + 256) * HH);
        float a = 0.f;
#pragma unroll 8
        for (int k4 = 0; k4 < HH / 4; ++k4) {
          float4 q = w[k4];
          float4 hv = *(const float4*)&lhid[k4 * 4];
          a = fmaf(hv.x, q.x, a); a = fmaf(hv.y, q.y, a);
          a = fmaf(hv.z, q.z, a); a = fmaf(hv.w, q.w, a);
        }
        v1 = a + bp2[tid + 256];
      }
      // row max (same reduction order as R2)
      float m = -INFINITY;
      if (tid < VV) m = fmaxf(m, v0);
      if (tid + 256 < VV) m = fmaxf(m, v1);
      for (int off = 32; off > 0; off >>= 1) m = fmaxf(m, __shfl_down(m, off, 64));
      if ((tid & 63) == 0) rf[tid >> 6] = m;
      __syncthreads();
      if (tid == 0) rf[4] = fmaxf(fmaxf(rf[0], rf[1]), fmaxf(rf[2], rf[3]));
      __syncthreads();
      m = rf[4];
      // sk = TF(rng_d, (0,1)); gumbel-argmax (first-index ties)
      unsigned sk0, sk1;
      tf2x32(rk0, rk1, 0u, 1u, sk0, sk1);
      float by = -INFINITY; int bc = 0x7fffffff;
      if (tid < VV) {
        unsigned o0, o1;
        tf2x32(sk0, sk1, 0u, (unsigned)(brow * VV + tid), o0, o1);
        unsigned bits = o0 ^ o1;
        float f = __uint_as_float(0x3f800000u | (bits >> 9)) - 1.0f;
        float u = (f > 0.f) ? f : 1.17549435e-38f;
        float g = (float)(-log(-log((double)u)));
        float y = v0 + g;
        if (y > by || (y == by && tid < bc)) { by = y; bc = tid; }
      }
      if (tid + 256 < VV) {
        int c = tid + 256;
        unsigned o0, o1;
        tf2x32(sk0, sk1, 0u, (unsigned)(brow * VV + c), o0, o1);
        unsigned bits = o0 ^ o1;
        float f = __uint_as_float(0x3f800000u | (bits >> 9)) - 1.0f;
        float u = (f > 0.f) ? f : 1.17549435e-38f;
        float g = (float)(-log(-log((double)u)));
        float y = v1 + g;
        if (y > by || (y == by && c < bc)) { by = y; bc = c; }
      }
      for (int off = 32; off > 0; off >>= 1) {
        float oy = __shfl_down(by, off, 64);
        int oc = __shfl_down(bc, off, 64);
        if (oy > by || (oy == by && oc < bc)) { by = oy; bc = oc; }
      }
      if ((tid & 63) == 0) { rf[tid >> 6] = by; ri[tid >> 6] = bc; }
      __syncthreads();
      if (tid == 0) {
        by = rf[0]; bc = ri[0];
        for (int w2 = 1; w2 < 4; ++w2)
          if (rf[w2] > by || (rf[w2] == by && ri[w2] < bc)) { by = rf[w2]; bc = ri[w2]; }
        stu_a((unsigned*)tok + brow, (unsigned)bc);
        out[(size_t)BB * TT * VV + (size_t)brow * TT + (d + 1)] = (float)bc;
      }
      __syncthreads();
      // softmax probs
      float e0 = 0.f, e1 = 0.f, ssum = 0.f;
      if (tid < VV) { e0 = expf(v0 - m); ssum += e0; }
      if (tid + 256 < VV) { e1 = expf(v1 - m); ssum += e1; }
      for (int off = 32; off > 0; off >>= 1) ssum += __shfl_down(ssum, off, 64);
      if ((tid & 63) == 0) rf[tid >> 6] = ssum;
      __syncthreads();
      if (tid == 0) rf[4] = (rf[0] + rf[1]) + (rf[2] + rf[3]);
      __syncthreads();
      float S = rf[4];
      float* orow = out + ((size_t)brow * TT + (d + 1)) * VV;
      if (tid < VV) orow[tid] = e0 / S;
      if (tid + 256 < VV) orow[tid + 256] = e1 / S;
    }
    // all WGs advance the key chain identically
    {
      unsigned n0, n1;
      tf2x32(rk0, rk1, 0u, 0u, n0, n1);
      rk0 = n0; rk1 = n1;
    }
    if (d < TT - 2) bar<256>(dflags, wg, ++ep);
  }
}

extern "C" void kernel_launch(void* const* d_in, const int* in_sizes, int n_in,
                              void* d_out, int out_size, void* d_ws, size_t ws_size,
                              hipStream_t stream) {
  (void)in_sizes; (void)n_in; (void)out_size; (void)ws_size;
  const float* input = (const float*)d_in[0];
  const float* e_emb = (const float*)d_in[1];
  const float* eWih0 = (const float*)d_in[2];
  const float* eWhh0 = (const float*)d_in[3];
  const float* ebih0 = (const float*)d_in[4];
  const float* ebhh0 = (const float*)d_in[5];
  const float* eWih1 = (const float*)d_in[6];
  const float* eWhh1 = (const float*)d_in[7];
  const float* ebih1 = (const float*)d_in[8];
  const float* ebhh1 = (const float*)d_in[9];
  const float* d_emb = (const float*)d_in[10];
  const float* dWih0 = (const float*)d_in[11];
  const float* dWhh0 = (const float*)d_in[12];
  const float* dbih0 = (const float*)d_in[13];
  const float* dbhh0 = (const float*)d_in[14];
  const float* dWih1 = (const float*)d_in[15];
  const float* dWhh1 = (const float*)d_in[16];
  const float* dbih1 = (const float*)d_in[17];
  const float* dbhh1 = (const float*)d_in[18];
  const float* Wp1   = (const float*)d_in[19];
  const float* bp1   = (const float*)d_in[20];
  const float* Wp2   = (const float*)d_in[21];
  const float* bp2   = (const float*)d_in[22];
  float* out = (float*)d_out;

  // ws layout (unchanged): xT [512][256*64] | h1 ping-pong | h2 ping-pong | tok
  float* xT = (float*)d_ws;
  float* h1buf = xT + (size_t)TT * EE * 64;
  float* h2buf = h1buf + 2 * HH * BB;
  int* tok = (int*)(h2buf + 2 * HH * BB);
  // Overlays on dead storage:
  //  - ebase: out probs rows (b=1,t=1..2) — dead until decoder d=1..2 C23,
  //    which runs after the encoder kernel completed. 512 words.
  //  - dflags: xT[0..255] — xT t=0 block only read at encoder t=0; zeroed
  //    inside k_enc at t==2. 256 words.
  //  - hid: xT+4096.. — xT fully dead during the decoder.
  unsigned* ebase = (unsigned*)(out + ((size_t)1 * TT + 1) * VV);
  unsigned* dflags = (unsigned*)xT;
  float* hid = xT + 4096;

  k_init<<<64, 256, 0, stream>>>(out, h1buf, h2buf, tok, ebase);
  k_xgemm<<<TT, 256, 0, stream>>>(input, e_emb, xT);
  k_enc<<<512, 256, 0, stream>>>(xT, h1buf, h2buf,
      eWih0, eWhh0, ebih0, ebhh0, eWih1, eWhh1, ebih1, ebhh1, ebase, dflags);
  k_dec<<<256, 256, 0, stream>>>(h1buf, h2buf, d_emb,
      dWih0, dWhh0, dbih0, dbhh0, dWih1, dWhh1, dbih1, dbhh1,
      Wp1, bp1, Wp2, bp2, out, tok, dflags, hid);
}

// Round 4
// 73415.906 us; speedup vs baseline: 1.6638x; 1.0199x over previous
//
#include <hip/hip_runtime.h>
#include <math.h>

// Seq2seq GRU encoder/decoder with exact JAX threefry sampling.
// R5 design: persistent + fenceless sc1 barriers + LDS-staged state tiles +
// batch-group factorization.
//   R3 post-mortem: phases were L3-REQUEST-bound: every wave re-read the
//   whole 128KB h-state via 8B sc1 loads (~128MB/phase grid-wide).
//   Fixes:
//   - WG owns j-block of 16 cols x batch-tile of 8: stages X[512k x 8b]
//     (16KB) in LDS once per phase via sc1 loads, reuses 16x from LDS
//     (conflict-free ds_read_b128). Grid sc1 traffic ~8-16MB/phase.
//   - Batches are independent end-to-end -> 8 groups of 8 batches, each
//     with its own 32-WG (dec) / 64-WG (enc) flag barrier. No global
//     coupling; groups drift and hide each other's latency.
//   - Every (j,b) output keeps the EXACT R3 fma chain (k-ascending, same
//     combine exprs) -> bit-identical output; absmax must stay exactly
//     1.525879e-05. Deviation = staging bug, not tolerance.

#define BB 64
#define TT 512
#define VV 390
#define EE 256
#define HH 512

// swizzled state layout: elem (k, b) at [(k>>2)*256 + b*4 + (k&3)]
#define SW(k, b) ((((k) >> 2) << 8) + ((b) << 2) + ((k) & 3))

static __device__ __forceinline__ void tf2x32(unsigned k0, unsigned k1,
                                              unsigned x0, unsigned x1,
                                              unsigned &o0, unsigned &o1) {
  unsigned ks2 = k0 ^ k1 ^ 0x1BD11BDAu;
  x0 += k0; x1 += k1;
#define TFR(r) x0 += x1; x1 = (x1 << (r)) | (x1 >> (32 - (r))); x1 ^= x0;
  TFR(13) TFR(15) TFR(26) TFR(6)
  x0 += k1; x1 += ks2 + 1u;
  TFR(17) TFR(29) TFR(16) TFR(24)
  x0 += ks2; x1 += k0 + 2u;
  TFR(13) TFR(15) TFR(26) TFR(6)
  x0 += k0; x1 += k1 + 3u;
  TFR(17) TFR(29) TFR(16) TFR(24)
  x0 += k1; x1 += ks2 + 4u;
  TFR(13) TFR(15) TFR(26) TFR(6)
  x0 += ks2; x1 += k0 + 5u;
#undef TFR
  o0 = x0; o1 = x1;
}

static __device__ __forceinline__ float sigm(float x) {
  return 1.0f / (1.0f + expf(-x));
}

// ---- agent-scope relaxed (sc1) helpers: coherent at L3, no fences ----
static __device__ __forceinline__ unsigned ldu_a(const unsigned* p) {
  return __hip_atomic_load((unsigned*)p, __ATOMIC_RELAXED,
                           __HIP_MEMORY_SCOPE_AGENT);
}
static __device__ __forceinline__ void stu_a(unsigned* p, unsigned v) {
  __hip_atomic_store(p, v, __ATOMIC_RELAXED, __HIP_MEMORY_SCOPE_AGENT);
}
static __device__ __forceinline__ float ldf_a(const float* p) {
  return __uint_as_float(ldu_a((const unsigned*)p));
}
static __device__ __forceinline__ void stf_a(float* p, float v) {
  stu_a((unsigned*)p, __float_as_uint(v));
}
static __device__ __forceinline__ float2 ldf2_a(const float* p) {
  unsigned long long v = __hip_atomic_load((unsigned long long*)p,
      __ATOMIC_RELAXED, __HIP_MEMORY_SCOPE_AGENT);
  return make_float2(__uint_as_float((unsigned)v),
                     __uint_as_float((unsigned)(v >> 32)));
}

// Stage X[all 512 k][b0..b0+7] (16KB) into LDS. Loads first into regs
// (one latency batch), then LDS writes. Thread i covers float2 slot
// (k4 = i>>4, bi = (i>>1)&7, h = i&1); LDS slot index == i (linear).
static __device__ __forceinline__ void stage512(const float* X, int b0,
                                                float2* L) {
  int tid = threadIdx.x;
  float2 v[8];
#pragma unroll
  for (int r = 0; r < 8; ++r) {
    int i = tid + (r << 8);
    v[r] = ldf2_a(X + ((i >> 4) << 8) + ((b0 + ((i >> 1) & 7)) << 2) +
                  ((i & 1) << 1));
  }
#pragma unroll
  for (int r = 0; r < 8; ++r) L[tid + (r << 8)] = v[r];
}

// 3-row dot over a staged LDS tile (K floats), lane's batch = bi.
// ds_read_b128 per k4: 8 distinct 16B addrs spanning 128B -> conflict-free.
// fma order identical to R3's dot3s_a (k ascending, u.x..u.w).
template <int K>
static __device__ __forceinline__ void dot3_lds(const float4* Lx, int bi,
    const float* __restrict__ w0, const float* __restrict__ w1,
    const float* __restrict__ w2, float &r0, float &r1, float &r2) {
  const float4* q0 = (const float4*)w0;
  const float4* q1 = (const float4*)w1;
  const float4* q2 = (const float4*)w2;
  float s0 = 0.f, s1 = 0.f, s2 = 0.f;
#pragma unroll
  for (int k4 = 0; k4 < (K >> 2); ++k4) {
    float4 x = Lx[(k4 << 3) + bi];
    float4 u0 = q0[k4], u1 = q1[k4], u2 = q2[k4];
    s0 = fmaf(x.x, u0.x, s0); s0 = fmaf(x.y, u0.y, s0); s0 = fmaf(x.z, u0.z, s0); s0 = fmaf(x.w, u0.w, s0);
    s1 = fmaf(x.x, u1.x, s1); s1 = fmaf(x.y, u1.y, s1); s1 = fmaf(x.z, u1.z, s1); s1 = fmaf(x.w, u1.w, s1);
    s2 = fmaf(x.x, u2.x, s2); s2 = fmaf(x.y, u2.y, s2); s2 = fmaf(x.z, u2.z, s2); s2 = fmaf(x.w, u2.w, s2);
  }
  r0 = s0; r1 = s1; r2 = s2;
}

template <int K>
static __device__ __forceinline__ float dot1_lds(const float4* Lx, int bi,
    const float* __restrict__ w) {
  const float4* q = (const float4*)w;
  float s = 0.f;
#pragma unroll
  for (int k4 = 0; k4 < (K >> 2); ++k4) {
    float4 x = Lx[(k4 << 3) + bi];
    float4 u = q[k4];
    s = fmaf(x.x, u.x, s); s = fmaf(x.y, u.y, s);
    s = fmaf(x.z, u.z, s); s = fmaf(x.w, u.w, s);
  }
  return s;
}

// 3-row dot over SWIZZLED read-only X (plain cached float4) — encoder xT.
template <int K>
static __device__ __forceinline__ void dot3s_p(const float* __restrict__ X, int b,
    const float* __restrict__ w0, const float* __restrict__ w1,
    const float* __restrict__ w2, float &r0, float &r1, float &r2) {
  const float4* q0 = (const float4*)w0;
  const float4* q1 = (const float4*)w1;
  const float4* q2 = (const float4*)w2;
  const float4* Xp = (const float4*)X;
  float s0 = 0.f, s1 = 0.f, s2 = 0.f;
#pragma unroll
  for (int k4 = 0; k4 < (K >> 2); ++k4) {
    float4 x = Xp[(k4 << 6) + b];
    float4 u0 = q0[k4], u1 = q1[k4], u2 = q2[k4];
    s0 = fmaf(x.x, u0.x, s0); s0 = fmaf(x.y, u0.y, s0); s0 = fmaf(x.z, u0.z, s0); s0 = fmaf(x.w, u0.w, s0);
    s1 = fmaf(x.x, u1.x, s1); s1 = fmaf(x.y, u1.y, s1); s1 = fmaf(x.z, u1.z, s1); s1 = fmaf(x.w, u1.w, s1);
    s2 = fmaf(x.x, u2.x, s2); s2 = fmaf(x.y, u2.y, s2); s2 = fmaf(x.z, u2.z, s2); s2 = fmaf(x.w, u2.w, s2);
  }
  r0 = s0; r1 = s1; r2 = s2;
}

// Per-lane contiguous row (embedding gather, read-only) — unchanged order.
template <int K>
static __device__ __forceinline__ void dot3_row(const float* __restrict__ xrow,
    const float* __restrict__ w0, const float* __restrict__ w1,
    const float* __restrict__ w2, float &r0, float &r1, float &r2) {
  const float4* xq = (const float4*)xrow;
  const float4* q0 = (const float4*)w0;
  const float4* q1 = (const float4*)w1;
  const float4* q2 = (const float4*)w2;
  float s0 = 0.f, s1 = 0.f, s2 = 0.f;
#pragma unroll
  for (int k4 = 0; k4 < (K >> 2); ++k4) {
    float4 x = xq[k4];
    float4 u0 = q0[k4], u1 = q1[k4], u2 = q2[k4];
    s0 = fmaf(x.x, u0.x, s0); s0 = fmaf(x.y, u0.y, s0); s0 = fmaf(x.z, u0.z, s0); s0 = fmaf(x.w, u0.w, s0);
    s1 = fmaf(x.x, u1.x, s1); s1 = fmaf(x.y, u1.y, s1); s1 = fmaf(x.z, u1.z, s1); s1 = fmaf(x.w, u1.w, s1);
    s2 = fmaf(x.x, u2.x, s2); s2 = fmaf(x.y, u2.y, s2); s2 = fmaf(x.z, u2.z, s2); s2 = fmaf(x.w, u2.w, s2);
  }
  r0 = s0; r1 = s1; r2 = s2;
}

// Group-local fenceless barrier over nwg WGs (flags in the group's own
// lines). Entry __syncthreads drains vmcnt: this WG's sc1 stores are at the
// coherent point before its flag publishes them.
static __device__ __forceinline__ void gbar(unsigned* f, int nwg, int wgi,
                                            unsigned ep) {
  __syncthreads();
  int tid = threadIdx.x;
  if (tid == 0) stu_a(f + wgi, ep);
  if (tid < 64) {
    bool ok;
    do {
      ok = true;
      for (int i = tid; i < nwg; i += 64) ok &= (ldu_a(f + i) >= ep);
    } while (!__all((int)ok));
  }
  __syncthreads();
}

__global__ __launch_bounds__(256) void k_init(float* out,
    float* h1buf, float* h2buf, int* tok, unsigned* ebase) {
  int wg = blockIdx.x, tid = threadIdx.x;
  for (int i = wg * 256 + tid; i < HH * BB; i += 64 * 256) {
    h1buf[i] = 0.f;  // slot 0 only (slot 1 always written before read)
    h2buf[i] = 0.f;
  }
  for (int v = tid; v < VV; v += 256)
    out[(size_t)wg * TT * VV + v] = (v == 388) ? 1.0f : 0.0f;
  if (wg == 0) {  // encoder flags: 8 groups x 64 = 512 words
    ebase[tid] = 0u;
    ebase[tid + 256] = 0u;
  }
  if (tid == 0) {
    out[(size_t)BB * TT * VV + (size_t)wg * TT] = 388.0f;
    tok[wg] = 388;
  }
}

// x_swz[t][(e>>2)*256 + b*4 + (e&3)] = sum_v input[b][t][v]*emb[v][e].
__global__ __launch_bounds__(256) void k_xgemm(const float* __restrict__ input,
    const float* __restrict__ emb, float* __restrict__ xT) {
  int t = blockIdx.x, tid = threadIdx.x;
  int s = tid >> 6, b = tid & 63;
  __shared__ float lin[64 * 65];
  float4 acc[16];
#pragma unroll
  for (int i = 0; i < 16; ++i) acc[i] = make_float4(0.f, 0.f, 0.f, 0.f);
  for (int k0 = 0; k0 < VV; k0 += 64) {
    int kmax = min(64, VV - k0);
    __syncthreads();
#pragma unroll
    for (int r = 0; r < 16; ++r) {
      int idx = r * 256 + tid;
      int b2 = idx >> 6, kk = idx & 63;
      if (kk < kmax)
        lin[kk * 65 + b2] = input[((size_t)b2 * TT + t) * VV + k0 + kk];
    }
    __syncthreads();
    for (int kk = 0; kk < kmax; ++kk) {
      float xv = lin[kk * 65 + b];
      const float4* er = (const float4*)(emb + (size_t)(k0 + kk) * EE);
#pragma unroll
      for (int i = 0; i < 16; ++i) {
        float4 w = er[s + 4 * i];
        acc[i].x = fmaf(xv, w.x, acc[i].x);
        acc[i].y = fmaf(xv, w.y, acc[i].y);
        acc[i].z = fmaf(xv, w.z, acc[i].z);
        acc[i].w = fmaf(xv, w.w, acc[i].w);
      }
    }
  }
  float* dst0 = xT + (size_t)t * (EE * 64);
#pragma unroll
  for (int i = 0; i < 16; ++i)
    *(float4*)(dst0 + (s + 4 * i) * 256 + 4 * b) = acc[i];
}

// Persistent encoder: 512 WGs = 8 groups x (32 layer0-WGs + 32 layer1-WGs).
// Group g owns batches b0..b0+7; WG owns 16 j-columns. Waves 0-1: ih-dot +
// finalize; waves 2-3: hh-dot -> LDS part. One group barrier per t.
__global__ __launch_bounds__(256, 2) void k_enc(
    const float* xT, float* h1buf, float* h2buf,
    const float* __restrict__ Wih0, const float* __restrict__ Whh0,
    const float* __restrict__ bih0, const float* __restrict__ bhh0,
    const float* __restrict__ Wih1, const float* __restrict__ Whh1,
    const float* __restrict__ bih1, const float* __restrict__ bhh1,
    unsigned* eflags, unsigned* dflags) {
  int wg = blockIdx.x, tid = threadIdx.x;
  int g = wg >> 6, wgi = wg & 63;
  int b0 = g << 3;
  int lay = wgi >> 5, j0 = (wgi & 31) << 4;
  int task = tid >> 7, l = tid & 127;
  int jj = l >> 3, bi = l & 7;
  int j = j0 + jj, b = b0 + bi;
  __shared__ float2 sX[2048];
  __shared__ float2 sY[2048];
  __shared__ float part[3][128];
  unsigned* gf = eflags + (g << 6);
  for (int t = 0; t <= TT; ++t) {
    const float* h1_r = h1buf + (t & 1) * (HH * BB);        // h1[t-1]
    float* h1_w = h1buf + ((t + 1) & 1) * (HH * BB);        // h1[t]
    if (lay == 0) {
      if (t < TT) {
        stage512(h1_r, b0, sX);
        __syncthreads();
        float ar = 0.f, az = 0.f, an = 0.f;
        if (task == 0) {
          dot3s_p<EE>(xT + (size_t)t * (EE * 64), b,
                      Wih0 + (size_t)j * EE, Wih0 + (size_t)(512 + j) * EE,
                      Wih0 + (size_t)(1024 + j) * EE, ar, az, an);
        } else {
          float hr, hz, hn;
          dot3_lds<HH>((const float4*)sX, bi,
                       Whh0 + (size_t)j * HH, Whh0 + (size_t)(512 + j) * HH,
                       Whh0 + (size_t)(1024 + j) * HH, hr, hz, hn);
          part[0][l] = hr; part[1][l] = hz; part[2][l] = hn;
        }
        __syncthreads();
        if (task == 0) {
          float hr = part[0][l], hz = part[1][l], hn = part[2][l];
          float r = sigm((ar + bih0[j]) + (hr + bhh0[j]));
          float z = sigm((az + bih0[512 + j]) + (hz + bhh0[512 + j]));
          float n = tanhf((an + bih0[1024 + j]) + r * (hn + bhh0[1024 + j]));
          float hp = ((const float*)sX)[((j >> 2) << 5) + (bi << 2) + (j & 3)];
          stf_a(h1_w + SW(j, b), (1.0f - z) * n + z * hp);
        }
      }
    } else {
      if (t >= 1) {  // layer1 processes step t-1
        const float* h2_r = h2buf + ((t + 1) & 1) * (HH * BB);  // h2[t-2]
        float* h2_w = h2buf + (t & 1) * (HH * BB);              // h2[t-1]
        stage512(h1_r, b0, sX);
        stage512(h2_r, b0, sY);
        __syncthreads();
        float ar = 0.f, az = 0.f, an = 0.f;
        if (task == 0) {
          dot3_lds<HH>((const float4*)sX, bi,   // input = h1[t-1]
                       Wih1 + (size_t)j * HH, Wih1 + (size_t)(512 + j) * HH,
                       Wih1 + (size_t)(1024 + j) * HH, ar, az, an);
        } else {
          float hr, hz, hn;
          dot3_lds<HH>((const float4*)sY, bi,
                       Whh1 + (size_t)j * HH, Whh1 + (size_t)(512 + j) * HH,
                       Whh1 + (size_t)(1024 + j) * HH, hr, hz, hn);
          part[0][l] = hr; part[1][l] = hz; part[2][l] = hn;
        }
        __syncthreads();
        if (task == 0) {
          float hr = part[0][l], hz = part[1][l], hn = part[2][l];
          float r = sigm((ar + bih1[j]) + (hr + bhh1[j]));
          float z = sigm((az + bih1[512 + j]) + (hz + bhh1[512 + j]));
          float n = tanhf((an + bih1[1024 + j]) + r * (hn + bhh1[1024 + j]));
          float hp = ((const float*)sY)[((j >> 2) << 5) + (bi << 2) + (j & 3)];
          stf_a(h2_w + SW(j, b), (1.0f - z) * n + z * hp);
        }
      }
    }
    // Zero this group's decoder flags (overlay xT floats [g*32, g*32+32),
    // which are exactly THIS group's k4=0 slice of xT[t=0] — its only reads
    // were at t=0, done before this group's t=1 barrier).
    if (t == 2 && wgi == 0 && tid < 32) stu_a(dflags + (g << 5) + tid, 0u);
    if (t < TT) gbar(gf, 64, wgi, (unsigned)(t + 1));
  }
}

// Persistent decoder: 256 WGs = 8 groups x 32 WGs (16 j-cols each).
// 4 group-local phases/step: A (layer0), B (layer1), C1 (Wp1+LeakyReLU),
// C23 (logits+sample+softmax, WGs wgi<8, one batch row each).
__global__ __launch_bounds__(256, 1) void k_dec(
    float* h1buf, float* h2buf,
    const float* __restrict__ demb,
    const float* __restrict__ dWih0, const float* __restrict__ dWhh0,
    const float* __restrict__ dbih0, const float* __restrict__ dbhh0,
    const float* __restrict__ dWih1, const float* __restrict__ dWhh1,
    const float* __restrict__ dbih1, const float* __restrict__ dbhh1,
    const float* __restrict__ Wp1, const float* __restrict__ bp1,
    const float* __restrict__ Wp2, const float* __restrict__ bp2,
    float* out, int* tok, unsigned* dflags, float* hid) {
  int wg = blockIdx.x, tid = threadIdx.x;
  int g = wg >> 5, wgi = wg & 31;
  int b0 = g << 3, j0 = wgi << 4;
  int task = tid >> 7, l = tid & 127;
  int jj = l >> 3, bi = l & 7;
  int j = j0 + jj, b = b0 + bi;
  __shared__ float2 sX[2048];
  __shared__ float2 sY[2048];
  __shared__ float part[3][128];
  __shared__ __align__(16) float lhid[HH];
  __shared__ float rf[8];
  __shared__ int ri[4];
  unsigned* gf = dflags + (g << 5);
  unsigned rk0 = 0u, rk1 = 42u;  // jax.random.key(42), chained in registers
  unsigned ep = 0u;
  for (int d = 0; d < TT - 1; ++d) {
    const float* h1_r = h1buf + (d & 1) * (HH * BB);
    float* h1_w = h1buf + ((d + 1) & 1) * (HH * BB);
    const float* h2_r = h2buf + (d & 1) * (HH * BB);
    float* h2_w = h2buf + ((d + 1) & 1) * (HH * BB);
    // ---------------- phase A: decoder layer0 ----------------
    {
      stage512(h1_r, b0, sX);
      __syncthreads();
      float ar = 0.f, az = 0.f, an = 0.f;
      if (task == 1) {
        float hr, hz, hn;
        dot3_lds<HH>((const float4*)sX, bi,
                     dWhh0 + (size_t)j * HH, dWhh0 + (size_t)(512 + j) * HH,
                     dWhh0 + (size_t)(1024 + j) * HH, hr, hz, hn);
        part[0][l] = hr; part[1][l] = hz; part[2][l] = hn;
      } else {
        int tk = (int)ldu_a((const unsigned*)tok + b);
        dot3_row<EE>(demb + (size_t)tk * EE,
                     dWih0 + (size_t)j * EE, dWih0 + (size_t)(512 + j) * EE,
                     dWih0 + (size_t)(1024 + j) * EE, ar, az, an);
      }
      __syncthreads();
      if (task == 0) {
        float hr = part[0][l], hz = part[1][l], hn = part[2][l];
        float r = sigm((ar + dbih0[j]) + (hr + dbhh0[j]));
        float z = sigm((az + dbih0[512 + j]) + (hz + dbhh0[512 + j]));
        float n = tanhf((an + dbih0[1024 + j]) + r * (hn + dbhh0[1024 + j]));
        float hp = ((const float*)sX)[((j >> 2) << 5) + (bi << 2) + (j & 3)];
        stf_a(h1_w + SW(j, b), (1.0f - z) * n + z * hp);
      }
    }
    gbar(gf, 32, wgi, ++ep);
    // ---------------- phase B: decoder layer1 ----------------
    {
      stage512(h1_w, b0, sX);
      stage512(h2_r, b0, sY);
      __syncthreads();
      float ar = 0.f, az = 0.f, an = 0.f;
      if (task == 0) {
        dot3_lds<HH>((const float4*)sX, bi,
                     dWih1 + (size_t)j * HH, dWih1 + (size_t)(512 + j) * HH,
                     dWih1 + (size_t)(1024 + j) * HH, ar, az, an);
      } else {
        float hr, hz, hn;
        dot3_lds<HH>((const float4*)sY, bi,
                     dWhh1 + (size_t)j * HH, dWhh1 + (size_t)(512 + j) * HH,
                     dWhh1 + (size_t)(1024 + j) * HH, hr, hz, hn);
        part[0][l] = hr; part[1][l] = hz; part[2][l] = hn;
      }
      __syncthreads();
      if (task == 0) {
        float hr = part[0][l], hz = part[1][l], hn = part[2][l];
        float r = sigm((ar + dbih1[j]) + (hr + dbhh1[j]));
        float z = sigm((az + dbih1[512 + j]) + (hz + dbhh1[512 + j]));
        float n = tanhf((an + dbih1[1024 + j]) + r * (hn + dbhh1[1024 + j]));
        float hp = ((const float*)sY)[((j >> 2) << 5) + (bi << 2) + (j & 3)];
        stf_a(h2_w + SW(j, b), (1.0f - z) * n + z * hp);
      }
    }
    gbar(gf, 32, wgi, ++ep);
    // ---------------- phase C1: hid = LeakyReLU(Wp1 . h2') ----------------
    {
      stage512(h2_w, b0, sX);
      __syncthreads();
      if (tid < 128) {
        float a = dot1_lds<HH>((const float4*)sX, bi, Wp1 + (size_t)j * HH);
        a += bp1[j];
        stf_a(hid + SW(j, b), (a >= 0.f) ? a : 0.1f * a);
      }
    }
    gbar(gf, 32, wgi, ++ep);
    // -------- phase C23: logits + max/gumbel/softmax (wgi < 8) --------
    if (wgi < 8) {
      int brow = b0 + wgi;
      if (tid < 128) {  // stage hid[:,brow] -> lhid (512 floats)
        float2 ha = ldf2_a(hid + tid * 256 + brow * 4);
        float2 hb = ldf2_a(hid + tid * 256 + brow * 4 + 2);
        lhid[4 * tid] = ha.x; lhid[4 * tid + 1] = ha.y;
        lhid[4 * tid + 2] = hb.x; lhid[4 * tid + 3] = hb.y;
      }
      __syncthreads();
      float v0 = 0.f, v1 = 0.f;
      if (tid < VV) {
        const float4* w = (const float4*)(Wp2 + (size_t)tid * HH);
        float a = 0.f;
#pragma unroll 8
        for (int k4 = 0; k4 < HH / 4; ++k4) {
          float4 q = w[k4];
          float4 hv = *(const float4*)&lhid[k4 * 4];
          a = fmaf(hv.x, q.x, a); a = fmaf(hv.y, q.y, a);
          a = fmaf(hv.z, q.z, a); a = fmaf(hv.w, q.w, a);
        }
        v0 = a + bp2[tid];
      }
      if (tid + 256 < VV) {
        const float4* w = (const float4*)(Wp2 + (size_t)(tid + 256) * HH);
        float a = 0.f;
#pragma unroll 8
        for (int k4 = 0; k4 < HH / 4; ++k4) {
          float4 q = w[k4];
          float4 hv = *(const float4*)&lhid[k4 * 4];
          a = fmaf(hv.x, q.x, a); a = fmaf(hv.y, q.y, a);
          a = fmaf(hv.z, q.z, a); a = fmaf(hv.w, q.w, a);
        }
        v1 = a + bp2[tid + 256];
      }
      // row max (same reduction order as R3)
      float m = -INFINITY;
      if (tid < VV) m = fmaxf(m, v0);
      if (tid + 256 < VV) m = fmaxf(m, v1);
      for (int off = 32; off > 0; off >>= 1) m = fmaxf(m, __shfl_down(m, off, 64));
      if ((tid & 63) == 0) rf[tid >> 6] = m;
      __syncthreads();
      if (tid == 0) rf[4] = fmaxf(fmaxf(rf[0], rf[1]), fmaxf(rf[2], rf[3]));
      __syncthreads();
      m = rf[4];
      // sk = TF(rng_d, (0,1)); gumbel-argmax (first-index ties)
      unsigned sk0, sk1;
      tf2x32(rk0, rk1, 0u, 1u, sk0, sk1);
      float by = -INFINITY; int bc = 0x7fffffff;
      if (tid < VV) {
        unsigned o0, o1;
        tf2x32(sk0, sk1, 0u, (unsigned)(brow * VV + tid), o0, o1);
        unsigned bits = o0 ^ o1;
        float f = __uint_as_float(0x3f800000u | (bits >> 9)) - 1.0f;
        float u = (f > 0.f) ? f : 1.17549435e-38f;
        float gg = (float)(-log(-log((double)u)));
        float y = v0 + gg;
        if (y > by || (y == by && tid < bc)) { by = y; bc = tid; }
      }
      if (tid + 256 < VV) {
        int c = tid + 256;
        unsigned o0, o1;
        tf2x32(sk0, sk1, 0u, (unsigned)(brow * VV + c), o0, o1);
        unsigned bits = o0 ^ o1;
        float f = __uint_as_float(0x3f800000u | (bits >> 9)) - 1.0f;
        float u = (f > 0.f) ? f : 1.17549435e-38f;
        float gg = (float)(-log(-log((double)u)));
        float y = v1 + gg;
        if (y > by || (y == by && c < bc)) { by = y; bc = c; }
      }
      for (int off = 32; off > 0; off >>= 1) {
        float oy = __shfl_down(by, off, 64);
        int oc = __shfl_down(bc, off, 64);
        if (oy > by || (oy == by && oc < bc)) { by = oy; bc = oc; }
      }
      if ((tid & 63) == 0) { rf[tid >> 6] = by; ri[tid >> 6] = bc; }
      __syncthreads();
      if (tid == 0) {
        by = rf[0]; bc = ri[0];
        for (int w2 = 1; w2 < 4; ++w2)
          if (rf[w2] > by || (rf[w2] == by && ri[w2] < bc)) { by = rf[w2]; bc = ri[w2]; }
        stu_a((unsigned*)tok + brow, (unsigned)bc);
        out[(size_t)BB * TT * VV + (size_t)brow * TT + (d + 1)] = (float)bc;
      }
      __syncthreads();
      // softmax probs
      float e0 = 0.f, e1 = 0.f, ssum = 0.f;
      if (tid < VV) { e0 = expf(v0 - m); ssum += e0; }
      if (tid + 256 < VV) { e1 = expf(v1 - m); ssum += e1; }
      for (int off = 32; off > 0; off >>= 1) ssum += __shfl_down(ssum, off, 64);
      if ((tid & 63) == 0) rf[tid >> 6] = ssum;
      __syncthreads();
      if (tid == 0) rf[4] = (rf[0] + rf[1]) + (rf[2] + rf[3]);
      __syncthreads();
      float S = rf[4];
      float* orow = out + ((size_t)brow * TT + (d + 1)) * VV;
      if (tid < VV) orow[tid] = e0 / S;
      if (tid + 256 < VV) orow[tid + 256] = e1 / S;
    }
    // all WGs advance the key chain identically
    {
      unsigned n0, n1;
      tf2x32(rk0, rk1, 0u, 0u, n0, n1);
      rk0 = n0; rk1 = n1;
    }
    if (d < TT - 2) gbar(gf, 32, wgi, ++ep);
  }
}

extern "C" void kernel_launch(void* const* d_in, const int* in_sizes, int n_in,
                              void* d_out, int out_size, void* d_ws, size_t ws_size,
                              hipStream_t stream) {
  (void)in_sizes; (void)n_in; (void)out_size; (void)ws_size;
  const float* input = (const float*)d_in[0];
  const float* e_emb = (const float*)d_in[1];
  const float* eWih0 = (const float*)d_in[2];
  const float* eWhh0 = (const float*)d_in[3];
  const float* ebih0 = (const float*)d_in[4];
  const float* ebhh0 = (const float*)d_in[5];
  const float* eWih1 = (const float*)d_in[6];
  const float* eWhh1 = (const float*)d_in[7];
  const float* ebih1 = (const float*)d_in[8];
  const float* ebhh1 = (const float*)d_in[9];
  const float* d_emb = (const float*)d_in[10];
  const float* dWih0 = (const float*)d_in[11];
  const float* dWhh0 = (const float*)d_in[12];
  const float* dbih0 = (const float*)d_in[13];
  const float* dbhh0 = (const float*)d_in[14];
  const float* dWih1 = (const float*)d_in[15];
  const float* dWhh1 = (const float*)d_in[16];
  const float* dbih1 = (const float*)d_in[17];
  const float* dbhh1 = (const float*)d_in[18];
  const float* Wp1   = (const float*)d_in[19];
  const float* bp1   = (const float*)d_in[20];
  const float* Wp2   = (const float*)d_in[21];
  const float* bp2   = (const float*)d_in[22];
  float* out = (float*)d_out;

  // ws layout (unchanged): xT [512][256*64] | h1 ping-pong | h2 ping-pong | tok
  float* xT = (float*)d_ws;
  float* h1buf = xT + (size_t)TT * EE * 64;
  float* h2buf = h1buf + 2 * HH * BB;
  int* tok = (int*)(h2buf + 2 * HH * BB);
  // Overlays on dead storage:
  //  - eflags: out probs rows (b=1, t=1..) — dead until decoder d<=2 C23,
  //    which runs after the encoder completed. 512 words, zeroed by k_init.
  //  - dflags: xT[0..255] — group g's words are group g's own k4=0 slice of
  //    xT[t=0]; zeroed group-locally inside k_enc at t==2. 8x32 words.
  //  - hid: xT+4096.. — xT fully dead during the decoder.
  unsigned* eflags = (unsigned*)(out + ((size_t)1 * TT + 1) * VV);
  unsigned* dflags = (unsigned*)xT;
  float* hid = xT + 4096;

  k_init<<<64, 256, 0, stream>>>(out, h1buf, h2buf, tok, eflags);
  k_xgemm<<<TT, 256, 0, stream>>>(input, e_emb, xT);
  k_enc<<<512, 256, 0, stream>>>(xT, h1buf, h2buf,
      eWih0, eWhh0, ebih0, ebhh0, eWih1, eWhh1, ebih1, ebhh1, eflags, dflags);
  k_dec<<<256, 256, 0, stream>>>(h1buf, h2buf, d_emb,
      dWih0, dWhh0, dbih0, dbhh0, dWih1, dWhh1, dbih1, dbhh1,
      Wp1, bp1, Wp2, bp2, out, tok, dflags, hid);
}